// Round 6
// baseline (504.549 us; speedup 1.0000x reference)
//
#include <hip/hip_runtime.h>
#include <hip/hip_fp16.h>

#define N_NODES 100000
#define IN_DIM 128
#define HID 64
#define NUM_GRAPHS 2048
#define CNE_MAX (1600000 + 7 * N_NODES)   // padded-to-8 CSR upper bound

typedef _Float16 h8 __attribute__((ext_vector_type(8)));
typedef float f4 __attribute__((ext_vector_type(4)));

__device__ __forceinline__ float2 u2f2(unsigned u) {
    __half2 h = *reinterpret_cast<__half2*>(&u);
    return __half22float2(h);
}

// ---------------- build phase (direct global atomics: L2 atomic throughput is ample) ----------------

// per-edge degree count; also zeroes the pad row (row N, 128 B) of tmp
__global__ __launch_bounds__(256) void deg_atomic(const int* __restrict__ dst,
                                                  int* __restrict__ pdeg,
                                                  unsigned* __restrict__ padrow, int E) {
    int i = blockIdx.x * blockDim.x + threadIdx.x;
    if (blockIdx.x == 0 && threadIdx.x < 32) padrow[threadIdx.x] = 0;
    int stride = gridDim.x * blockDim.x;
    for (int e = i; e < E; e += stride) atomicAdd(&pdeg[dst[e]], 1);
}

// phase 1: per-block (1024 elems) inclusive scan + block sums; pad8 applied when flagged
__global__ void scan1(const int* __restrict__ counts, int* __restrict__ out1,
                      int* __restrict__ bsum, int n, int pad8) {
    __shared__ int s[256];
    int t = threadIdx.x;
    int base = blockIdx.x * 1024 + t * 4;
    int v[4];
#pragma unroll
    for (int i = 0; i < 4; i++) {
        int c = (base + i < n) ? counts[base + i] : 0;
        v[i] = pad8 ? ((c + 7) & ~7) : c;
    }
    int tsum = v[0] + v[1] + v[2] + v[3];
    s[t] = tsum;
    __syncthreads();
    for (int off = 1; off < 256; off <<= 1) {
        int tv = (t >= off) ? s[t - off] : 0;
        __syncthreads();
        s[t] += tv;
        __syncthreads();
    }
    int excl = s[t] - tsum;
    if (t == 255) bsum[blockIdx.x] = s[255];
    int run = excl;
#pragma unroll
    for (int i = 0; i < 4; i++) {
        run += v[i];
        if (base + i < n) out1[base + i] = run;
    }
}

// scan of block sums (nb <= 256) done redundantly per block in LDS (no extra dispatch)
__device__ __forceinline__ void inline_bscan(const int* __restrict__ bsum, int nb, int* s) {
    int t = threadIdx.x;
    int v = (t < nb) ? bsum[t] : 0;
    s[t] = v;
    __syncthreads();
    for (int off = 1; off < 256; off <<= 1) {
        int tv = (t >= off) ? s[t - off] : 0;
        __syncthreads();
        s[t] += tv;
        __syncthreads();
    }
    int excl = s[t] - v;
    __syncthreads();
    s[t] = excl;
    __syncthreads();
}

// finalize row_ptr; also emit dis = rsqrt(deg+1) and fill cursor cur = row start
// (row start = row_ptr[i+1] - pad8(deg_i), since padded sizes are what got scanned)
__global__ __launch_bounds__(256) void scan3d(int* __restrict__ row_ptr,
                                              const int* __restrict__ bsum, int nb,
                                              const int* __restrict__ pdeg,
                                              int* __restrict__ cur,
                                              float* __restrict__ dis, int n) {
    __shared__ int s[256];
    inline_bscan(bsum, nb, s);
    int i = blockIdx.x * blockDim.x + threadIdx.x;
    if (i == 0) row_ptr[0] = 0;
    if (i < n) {
        int v = row_ptr[i + 1] + s[i >> 10];
        row_ptr[i + 1] = v;
        int dg = pdeg[i];
        cur[i] = v - ((dg + 7) & ~7);
        dis[i] = rsqrtf((float)(dg + 1));
    }
}

// cne holds BYTE offsets (src * 128); pad slots -> N_NODES*128 (zero row).
// phase 1 (edges): pos = atomicAdd(cursor), scatter src offset. phase 2 (rows): fill the
// <=7 pad slots with Z. Slot sets are disjoint -> concurrent phases are race-free.
__global__ __launch_bounds__(256) void fill_atomic(const int* __restrict__ src,
                                                   const int* __restrict__ dst,
                                                   int* __restrict__ cur,
                                                   const int* __restrict__ row_ptr,
                                                   const int* __restrict__ pdeg,
                                                   unsigned* __restrict__ cne, int E, int n) {
    int i = blockIdx.x * blockDim.x + threadIdx.x;
    int stride = gridDim.x * blockDim.x;
    const unsigned Z = (unsigned)N_NODES << 7;
    for (int e = i; e < E; e += stride) {
        int d = dst[e];
        int pos = atomicAdd(&cur[d], 1);
        cne[pos] = (unsigned)src[e] << 7;
    }
    for (int r = i; r < n; r += stride) {
        int dg = pdeg[r];
        int end = row_ptr[r + 1];
        for (int k = end - ((dg + 7) & ~7) + dg; k < end; k++) cne[k] = Z;
    }
}

// ---------------- per-layer compute ----------------

// MFMA GEMM: out[row][col] = (half) dis[row] * sum_k X[row][k] * W[k][col]
// XT = float (layer 1) or _Float16 (h from previous layer; A-frag = direct 16 B load).
template <int K, typename XT>
__global__ __launch_bounds__(256) void gemm_mfma(const XT* __restrict__ X,
                                                 const float* __restrict__ W,
                                                 const float* __restrict__ dis,
                                                 __half* __restrict__ out, int n) {
    const int KS = K / 32;
    int wave = threadIdx.x >> 6, lane = threadIdx.x & 63;
    int quad = lane >> 4, l16 = lane & 15;
    h8 b[4][KS];
#pragma unroll
    for (int ct = 0; ct < 4; ct++)
#pragma unroll
        for (int ks = 0; ks < KS; ks++)
#pragma unroll
            for (int j = 0; j < 8; j++)
                b[ct][ks][j] = (_Float16)W[(ks * 32 + quad * 8 + j) * HID + ct * 16 + l16];
    int ntile = n >> 4;
    int wpb = blockDim.x >> 6;
    int stride = gridDim.x * wpb;
    for (int rt = blockIdx.x * wpb + wave; rt < ntile; rt += stride) {
        int row0 = rt << 4;
        const XT* xr = X + (size_t)(row0 + l16) * K + quad * 8;
        f4 acc[4];
#pragma unroll
        for (int ct = 0; ct < 4; ct++) acc[ct] = (f4)(0.f);
#pragma unroll
        for (int ks = 0; ks < KS; ks++) {
            h8 a;
            if constexpr (__is_same(XT, float)) {
                float4 xa = *(const float4*)(xr + ks * 32);
                float4 xb = *(const float4*)(xr + ks * 32 + 4);
                a[0] = (_Float16)xa.x; a[1] = (_Float16)xa.y;
                a[2] = (_Float16)xa.z; a[3] = (_Float16)xa.w;
                a[4] = (_Float16)xb.x; a[5] = (_Float16)xb.y;
                a[6] = (_Float16)xb.z; a[7] = (_Float16)xb.w;
            } else {
                a = *(const h8*)(xr + ks * 32);
            }
#pragma unroll
            for (int ct = 0; ct < 4; ct++)
                acc[ct] = __builtin_amdgcn_mfma_f32_16x16x32_f16(a, b[ct][ks], acc[ct], 0, 0, 0);
        }
        int r0 = row0 + quad * 4;
        float4 dv = *(const float4*)(dis + r0);
        float dd[4] = {dv.x, dv.y, dv.z, dv.w};
#pragma unroll
        for (int reg = 0; reg < 4; reg++) {
            __half* orow = out + (size_t)(r0 + reg) * HID + l16;
            orow[0]  = __float2half(dd[reg] * acc[0][reg]);
            orow[16] = __float2half(dd[reg] * acc[1][reg]);
            orow[32] = __float2half(dd[reg] * acc[2][reg]);
            orow[48] = __float2half(dd[reg] * acc[3][reg]);
        }
    }
}

// out[row] = relu( dis[row] * (tmp[row] + sum_cols tmp[col]) + bias ); pads read zero row N.
// Quad-row layout: 64 lanes = 16 col-quads (m4, 8B = 4 cols) x 4 rows (rq). Each lane
// processes ALL 8 edges of its row's group as uint2. Task-level software pipeline: next
// task's row_ptr prefetched during gathers; first idx uint4s pre-resolved before the store.
template <typename OutT>
__global__ __launch_bounds__(256) void aggregate4(const __half* __restrict__ tmp,
                                                  const float* __restrict__ dis,
                                                  const int* __restrict__ row_ptr,
                                                  const unsigned* __restrict__ cne,
                                                  const float* __restrict__ bias,
                                                  OutT* __restrict__ out, int n) {
    int wave = threadIdx.x >> 6, lane = threadIdx.x & 63;
    int m4 = lane & 15, rq = lane >> 4;
    const char* tb = (const char*)tmp + 8 * m4;   // lane's 4-col byte base
    float4 blv = *(const float4*)(bias + 4 * m4);
    int wpb = blockDim.x >> 6;
    int stride = gridDim.x * wpb;
    int ntask = n >> 2;                            // 4 rows per task
    const unsigned Z = (unsigned)N_NODES << 7;     // zero pad row byte offset
    int t = blockIdx.x * wpb + wave;
    if (t >= ntask) return;
    int row = 4 * t + rq;
    int sE = row_ptr[row], eE = row_ptr[row + 1];
    uint4 A0, A1;
    if (sE < eE) {
        const uint4* ip0 = (const uint4*)(cne + sE);
        A0 = ip0[0]; A1 = ip0[1];
    } else {
        A0 = make_uint4(Z, Z, Z, Z); A1 = make_uint4(Z, Z, Z, Z);
    }
    while (true) {
        row = 4 * t + rq;
        float dr = dis[row];
        uint2 g0 = *(const uint2*)(tb + A0.x);
        uint2 g1 = *(const uint2*)(tb + A0.y);
        uint2 g2 = *(const uint2*)(tb + A0.z);
        uint2 g3 = *(const uint2*)(tb + A0.w);
        uint2 g4 = *(const uint2*)(tb + A1.x);
        uint2 g5 = *(const uint2*)(tb + A1.y);
        uint2 g6 = *(const uint2*)(tb + A1.z);
        uint2 g7 = *(const uint2*)(tb + A1.w);
        int tn = t + stride;
        int sN = 0, eN = 0;
        if (tn < ntask) {
            int rn = 4 * tn + rq;
            sN = row_ptr[rn]; eN = row_ptr[rn + 1];
        }
        int ng = (eE - sE) >> 3;
        float a0 = 0.f, a1 = 0.f, a2 = 0.f, a3 = 0.f;
        const uint4* ip = (const uint4*)(cne + sE);
        uint4 B0, B1;
        if (ng > 1) { B0 = ip[2]; B1 = ip[3]; }
        for (int g = 1; g < ng; g++) {
            uint2 u0 = *(const uint2*)(tb + B0.x);
            uint2 u1 = *(const uint2*)(tb + B0.y);
            uint2 u2 = *(const uint2*)(tb + B0.z);
            uint2 u3 = *(const uint2*)(tb + B0.w);
            uint2 u4 = *(const uint2*)(tb + B1.x);
            uint2 u5 = *(const uint2*)(tb + B1.y);
            uint2 u6 = *(const uint2*)(tb + B1.z);
            uint2 u7 = *(const uint2*)(tb + B1.w);
            if (g + 1 < ng) { B0 = ip[2 * g + 2]; B1 = ip[2 * g + 3]; }
            float2 f;
            f = u2f2(g0.x); a0 += f.x; a1 += f.y; f = u2f2(g0.y); a2 += f.x; a3 += f.y;
            f = u2f2(g1.x); a0 += f.x; a1 += f.y; f = u2f2(g1.y); a2 += f.x; a3 += f.y;
            f = u2f2(g2.x); a0 += f.x; a1 += f.y; f = u2f2(g2.y); a2 += f.x; a3 += f.y;
            f = u2f2(g3.x); a0 += f.x; a1 += f.y; f = u2f2(g3.y); a2 += f.x; a3 += f.y;
            f = u2f2(g4.x); a0 += f.x; a1 += f.y; f = u2f2(g4.y); a2 += f.x; a3 += f.y;
            f = u2f2(g5.x); a0 += f.x; a1 += f.y; f = u2f2(g5.y); a2 += f.x; a3 += f.y;
            f = u2f2(g6.x); a0 += f.x; a1 += f.y; f = u2f2(g6.y); a2 += f.x; a3 += f.y;
            f = u2f2(g7.x); a0 += f.x; a1 += f.y; f = u2f2(g7.y); a2 += f.x; a3 += f.y;
            g0 = u0; g1 = u1; g2 = u2; g3 = u3;
            g4 = u4; g5 = u5; g6 = u6; g7 = u7;
        }
        {
            float2 f;
            f = u2f2(g0.x); a0 += f.x; a1 += f.y; f = u2f2(g0.y); a2 += f.x; a3 += f.y;
            f = u2f2(g1.x); a0 += f.x; a1 += f.y; f = u2f2(g1.y); a2 += f.x; a3 += f.y;
            f = u2f2(g2.x); a0 += f.x; a1 += f.y; f = u2f2(g2.y); a2 += f.x; a3 += f.y;
            f = u2f2(g3.x); a0 += f.x; a1 += f.y; f = u2f2(g3.y); a2 += f.x; a3 += f.y;
            f = u2f2(g4.x); a0 += f.x; a1 += f.y; f = u2f2(g4.y); a2 += f.x; a3 += f.y;
            f = u2f2(g5.x); a0 += f.x; a1 += f.y; f = u2f2(g5.y); a2 += f.x; a3 += f.y;
            f = u2f2(g6.x); a0 += f.x; a1 += f.y; f = u2f2(g6.y); a2 += f.x; a3 += f.y;
            f = u2f2(g7.x); a0 += f.x; a1 += f.y; f = u2f2(g7.y); a2 += f.x; a3 += f.y;
        }
        if (sN < eN) {
            const uint4* ipn = (const uint4*)(cne + sN);
            A0 = ipn[0]; A1 = ipn[1];
        } else {
            A0 = make_uint4(Z, Z, Z, Z); A1 = make_uint4(Z, Z, Z, Z);
        }
        uint2 sv = *(const uint2*)(tb + (size_t)row * 128);
        float2 s01 = u2f2(sv.x), s23 = u2f2(sv.y);
        float v0 = fmaxf(dr * (s01.x + a0) + blv.x, 0.f);
        float v1 = fmaxf(dr * (s01.y + a1) + blv.y, 0.f);
        float v2 = fmaxf(dr * (s23.x + a2) + blv.z, 0.f);
        float v3 = fmaxf(dr * (s23.y + a3) + blv.w, 0.f);
        if constexpr (__is_same(OutT, __half)) {
            __half2 p01 = __floats2half2_rn(v0, v1);
            __half2 p23 = __floats2half2_rn(v2, v3);
            *(uint2*)((char*)out + (size_t)row * 128 + 8 * m4) =
                make_uint2(*(unsigned*)&p01, *(unsigned*)&p23);
        } else {
            *(float4*)(out + (size_t)row * HID + 4 * m4) = make_float4(v0, v1, v2, v3);
        }
        if (tn >= ntask) break;
        t = tn; sE = sN; eE = eN;
    }
}

__global__ __launch_bounds__(256) void pool_kernel(const float* __restrict__ h,
                                                   const int* __restrict__ batch,
                                                   const float* __restrict__ Wout,
                                                   const float* __restrict__ bout,
                                                   float* __restrict__ d_out, int n) {
    __shared__ float ssum[4][64];
    __shared__ float smax[4][64];
    int g = blockIdx.x;
    int wave = threadIdx.x >> 6, j = threadIdx.x & 63;
    int lo = 0, hi = n;
    while (lo < hi) { int mid = (lo + hi) >> 1; if (batch[mid] < g) lo = mid + 1; else hi = mid; }
    int start = lo;
    hi = n;
    while (lo < hi) { int mid = (lo + hi) >> 1; if (batch[mid] < g + 1) lo = mid + 1; else hi = mid; }
    int end = lo;

    float sum = 0.f, mx = 0.f;
    for (int i = start + wave; i < end; i += 4) {
        float v = h[(size_t)i * HID + j];
        sum += v;
        mx = fmaxf(mx, v);
    }
    ssum[wave][j] = sum;
    smax[wave][j] = mx;
    __syncthreads();
    if (wave == 0) {
        sum = (ssum[0][j] + ssum[1][j]) + (ssum[2][j] + ssum[3][j]);
        mx = fmaxf(fmaxf(smax[0][j], smax[1][j]), fmaxf(smax[2][j], smax[3][j]));
        float cnt = (float)(end - start);
        float mean = sum / fmaxf(cnt, 1.f);
        float* pooled = d_out + NUM_GRAPHS;
        pooled[(size_t)g * (2 * HID) + j] = mean;
        pooled[(size_t)g * (2 * HID) + HID + j] = mx;
        float c = mean * Wout[j] + mx * Wout[HID + j];
#pragma unroll
        for (int off = 32; off; off >>= 1) c += __shfl_down(c, off);
        if (j == 0) d_out[g] = c + bout[0];
    }
}

// ---------------- launch ----------------

extern "C" void kernel_launch(void* const* d_in, const int* in_sizes, int n_in,
                              void* d_out, int out_size, void* d_ws, size_t ws_size,
                              hipStream_t stream) {
    const float* x    = (const float*)d_in[0];
    const int*   edge = (const int*)d_in[1];
    const int*   batch= (const int*)d_in[2];
    const float* W1 = (const float*)d_in[3];  const float* b1 = (const float*)d_in[4];
    const float* W2 = (const float*)d_in[5];  const float* b2 = (const float*)d_in[6];
    const float* W3 = (const float*)d_in[7];  const float* b3 = (const float*)d_in[8];
    const float* W4 = (const float*)d_in[9];  const float* b4 = (const float*)d_in[10];
    const float* Wout = (const float*)d_in[11]; const float* bout = (const float*)d_in[12];
    float* out = (float*)d_out;

    const int N = N_NODES;
    const int E = in_sizes[1] / 2;
    const int* src = edge;
    const int* dst = edge + E;

    char* p = (char*)d_ws;
    auto alloc = [&](size_t bytes) -> char* {
        char* r = p;
        p += (bytes + 255) & ~(size_t)255;
        return r;
    };
    int*      pdeg     = (int*)alloc((size_t)N * 4);
    int*      row_ptr  = (int*)alloc((size_t)(N + 1) * 4);
    int*      cur      = (int*)alloc((size_t)N * 4);
    unsigned* cne      = (unsigned*)alloc((size_t)CNE_MAX * 4);
    float*    dis      = (float*)alloc((size_t)N * 4);
    int*      bsum     = (int*)alloc(256 * 4);
    __half*   tmp      = (__half*)alloc((size_t)(N + 1) * HID * 2);
    float*    hA       = (float*)alloc((size_t)N * HID * 4);
    __half*   hH       = (__half*)hA;   // fp16 h aliases front of hA (hA dead until agg4)

    unsigned* padrow = (unsigned*)(tmp + (size_t)N * HID);

    hipMemsetAsync(pdeg, 0, (size_t)N * 4, stream);
    deg_atomic<<<2048, 256, 0, stream>>>(dst, pdeg, padrow, E);
    int nb = (N + 1023) / 1024;   // 98
    scan1<<<nb, 256, 0, stream>>>(pdeg, row_ptr + 1, bsum, N, 1);
    scan3d<<<(N + 255) / 256, 256, 0, stream>>>(row_ptr, bsum, nb, pdeg, cur, dis, N);
    fill_atomic<<<2048, 256, 0, stream>>>(src, dst, cur, row_ptr, pdeg, cne, E, N);

    const int AGG_BLOCKS = 2048;
    const int GEMM_BLOCKS = 1024;

    gemm_mfma<IN_DIM, float><<<GEMM_BLOCKS, 256, 0, stream>>>(x, W1, dis, tmp, N);
    aggregate4<__half><<<AGG_BLOCKS, 256, 0, stream>>>(tmp, dis, row_ptr, cne, b1, hH, N);
    gemm_mfma<HID, _Float16><<<GEMM_BLOCKS, 256, 0, stream>>>((_Float16*)hH, W2, dis, tmp, N);
    aggregate4<__half><<<AGG_BLOCKS, 256, 0, stream>>>(tmp, dis, row_ptr, cne, b2, hH, N);
    gemm_mfma<HID, _Float16><<<GEMM_BLOCKS, 256, 0, stream>>>((_Float16*)hH, W3, dis, tmp, N);
    aggregate4<__half><<<AGG_BLOCKS, 256, 0, stream>>>(tmp, dis, row_ptr, cne, b3, hH, N);
    gemm_mfma<HID, _Float16><<<GEMM_BLOCKS, 256, 0, stream>>>((_Float16*)hH, W4, dis, tmp, N);
    aggregate4<float><<<AGG_BLOCKS, 256, 0, stream>>>(tmp, dis, row_ptr, cne, b4, hA, N);

    pool_kernel<<<NUM_GRAPHS, 256, 0, stream>>>(hA, batch, Wout, bout, out, N);
}

// Round 7
// 410.332 us; speedup vs baseline: 1.2296x; 1.2296x over previous
//
#include <hip/hip_runtime.h>
#include <hip/hip_fp16.h>

#define N_NODES 100000
#define IN_DIM 128
#define HID 64
#define NUM_GRAPHS 2048
#define CNE_MAX (1600000 + 7 * N_NODES)   // padded-to-8 CSR upper bound
#define BROWS 128                          // rows per bucket
#define NBUCK ((N_NODES + BROWS - 1) / BROWS)   // 782
#define NCHUNK 256                         // edge chunks (one block each)
#define TOTP (NBUCK * NCHUNK)              // 200192 partial counters
#define CAP 4096                           // LDS staging entries per bucket

typedef _Float16 h8 __attribute__((ext_vector_type(8)));
typedef float f4 __attribute__((ext_vector_type(4)));

// h/tmp live in 4 column-slices of 16 cols: [slice][(N+1) rows][16]. One slice = 3.2 MB
// (fits a 4 MiB per-XCD L2). SLICE_E = elements per slice (same count for half and float).
#define SLICE_E ((size_t)(N_NODES + 1) * 16)

__device__ __forceinline__ float2 u2f2(unsigned u) {
    __half2 h = *reinterpret_cast<__half2*>(&u);
    return __half22float2(h);
}

// ---------------- build phase (LDS-bucketed, NO per-edge global atomics — round-6 showed
// direct global scatter costs 100+ MB of write-allocate traffic at 0.87 TB/s) ----------------

// also zeroes the pad row (row N, 32 B) of all 4 tmp slices (replaces a memset dispatch)
__global__ __launch_bounds__(256) void hist_partial(const int* __restrict__ dst,
                                                    int* __restrict__ partial,
                                                    int E, int chunk,
                                                    unsigned* __restrict__ tmppad) {
    __shared__ int lh[NBUCK];
    int t = threadIdx.x, c = blockIdx.x;
    if (c == 0 && t < 32)
        tmppad[(size_t)(t >> 3) * ((N_NODES + 1) * 8) + (size_t)N_NODES * 8 + (t & 7)] = 0;
    for (int b = t; b < NBUCK; b += 256) lh[b] = 0;
    __syncthreads();
    int lo = c * chunk, hi = min(lo + chunk, E);
    for (int i = lo + t; i < hi; i += 256) atomicAdd(&lh[dst[i] >> 7], 1);
    __syncthreads();
    for (int b = t; b < NBUCK; b += 256) partial[b * NCHUNK + c] = lh[b];
}

// phase 1: per-block (1024 elems) inclusive scan + block sums; pad8 applied when flagged
__global__ void scan1(const int* __restrict__ counts, int* __restrict__ out1,
                      int* __restrict__ bsum, int n, int pad8) {
    __shared__ int s[256];
    int t = threadIdx.x;
    int base = blockIdx.x * 1024 + t * 4;
    int v[4];
#pragma unroll
    for (int i = 0; i < 4; i++) {
        int c = (base + i < n) ? counts[base + i] : 0;
        v[i] = pad8 ? ((c + 7) & ~7) : c;
    }
    int tsum = v[0] + v[1] + v[2] + v[3];
    s[t] = tsum;
    __syncthreads();
    for (int off = 1; off < 256; off <<= 1) {
        int tv = (t >= off) ? s[t - off] : 0;
        __syncthreads();
        s[t] += tv;
        __syncthreads();
    }
    int excl = s[t] - tsum;
    if (t == 255) bsum[blockIdx.x] = s[255];
    int run = excl;
#pragma unroll
    for (int i = 0; i < 4; i++) {
        run += v[i];
        if (base + i < n) out1[base + i] = run;
    }
}

// scan of block sums (nb <= 256) done redundantly per block in LDS (removes scan2 dispatch)
__device__ __forceinline__ void inline_bscan(const int* __restrict__ bsum, int nb, int* s) {
    int t = threadIdx.x;
    int v = (t < nb) ? bsum[t] : 0;
    s[t] = v;
    __syncthreads();
    for (int off = 1; off < 256; off <<= 1) {
        int tv = (t >= off) ? s[t - off] : 0;
        __syncthreads();
        s[t] += tv;
        __syncthreads();
    }
    int excl = s[t] - v;
    __syncthreads();
    s[t] = excl;
    __syncthreads();
}

__global__ __launch_bounds__(256) void scan3(int* __restrict__ row_ptr,
                                             const int* __restrict__ bsum, int nb, int n) {
    __shared__ int s[256];
    inline_bscan(bsum, nb, s);
    int i = blockIdx.x * blockDim.x + threadIdx.x;
    if (i == 0) row_ptr[0] = 0;
    if (i < n) row_ptr[i + 1] += s[i >> 10];
}

__global__ __launch_bounds__(256) void scan3p(const int* __restrict__ partial,
                                              const int* __restrict__ pincl,
                                              const int* __restrict__ bsum, int nb,
                                              int* __restrict__ base,
                                              int* __restrict__ part_off, int E) {
    __shared__ int s[256];
    inline_bscan(bsum, nb, s);
    int i = blockIdx.x * blockDim.x + threadIdx.x;
    if (i < TOTP) {
        int v = pincl[i] + s[i >> 10] - partial[i];
        base[i] = v;
        if ((i & (NCHUNK - 1)) == 0) part_off[i / NCHUNK] = v;
    }
    if (i == 0) part_off[NBUCK] = E;
}

__global__ __launch_bounds__(256) void partition_edges(const int* __restrict__ src,
                                                       const int* __restrict__ dst,
                                                       const int* __restrict__ base,
                                                       unsigned* __restrict__ part,
                                                       int E, int chunk) {
    __shared__ int cur[NBUCK];
    int t = threadIdx.x, c = blockIdx.x;
    for (int b = t; b < NBUCK; b += 256) cur[b] = base[b * NCHUNK + c];
    __syncthreads();
    int lo = c * chunk, hi = min(lo + chunk, E);
    for (int i = lo + t; i < hi; i += 256) {
        int s = src[i], d = dst[i];
        int pos = atomicAdd(&cur[d >> 7], 1);
        part[pos] = (unsigned)s | ((unsigned)(d & (BROWS - 1)) << 17);
    }
}

__global__ __launch_bounds__(256) void deg_dis(const unsigned* __restrict__ part,
                                               const int* __restrict__ part_off,
                                               int* __restrict__ pdeg,
                                               float* __restrict__ dis, int n) {
    __shared__ int cnt[BROWS];
    int t = threadIdx.x, b = blockIdx.x;
    int r0 = b * BROWS;
    if (t < BROWS) cnt[t] = 0;
    __syncthreads();
    for (int i = part_off[b] + t; i < part_off[b + 1]; i += 256)
        atomicAdd(&cnt[part[i] >> 17], 1);
    __syncthreads();
    int nrows = min(BROWS, n - r0);
    if (t < nrows) {
        int dg = cnt[t];
        pdeg[r0 + t] = dg;                          // raw; scan1 applies pad8
        dis[r0 + t] = rsqrtf((float)(dg + 1));
    }
}

// cne holds SLICE-LOCAL BYTE offsets (src * 32); pad slots -> N_NODES*32 (zero row).
__global__ __launch_bounds__(256) void build_csr(const unsigned* __restrict__ part,
                                                 const int* __restrict__ part_off,
                                                 const int* __restrict__ row_ptr,
                                                 unsigned* __restrict__ cne, int n) {
    __shared__ int fill[BROWS];
    __shared__ unsigned stage[CAP];
    int b = blockIdx.x;
    int r0 = b * BROWS;
    int t = threadIdx.x;
    int nrows = min(BROWS, n - r0);
    int base = row_ptr[r0];
    int region = row_ptr[r0 + nrows] - base;
    for (int r = t; r < nrows; r += 256) fill[r] = row_ptr[r0 + r] - base;
    int i0 = part_off[b], i1 = part_off[b + 1];
    if (region <= CAP) {
        for (int i = t; i < region; i += 256) stage[i] = (unsigned)N_NODES << 5;
        __syncthreads();
        for (int i = i0 + t; i < i1; i += 256) {
            unsigned pe = part[i];
            int pos = atomicAdd(&fill[pe >> 17], 1);
            stage[pos] = (pe & 0x1FFFFu) << 5;
        }
        __syncthreads();
        for (int i = t; i < region; i += 256) cne[base + i] = stage[i];
    } else {
        for (int i = t; i < region; i += 256) cne[base + i] = (unsigned)N_NODES << 5;
        __syncthreads();
        for (int i = i0 + t; i < i1; i += 256) {
            unsigned pe = part[i];
            int pos = atomicAdd(&fill[pe >> 17], 1);
            cne[base + pos] = (pe & 0x1FFFFu) << 5;
        }
    }
}

// ---------------- per-layer compute ----------------

// MFMA GEMM: out[row][col] = (half) dis[row] * sum_k X[row][k] * W[k][col]
// SIN: X is in sliced-half layout; else X is row-major float (layer 1).
// Output always sliced-half. Same MFMA path / rounding points as verified kernel.
template <int K, typename XT, bool SIN>
__global__ __launch_bounds__(256) void gemm_mfma(const XT* __restrict__ X,
                                                 const float* __restrict__ W,
                                                 const float* __restrict__ dis,
                                                 __half* __restrict__ out, int n) {
    const int KS = K / 32;
    int wave = threadIdx.x >> 6, lane = threadIdx.x & 63;
    int quad = lane >> 4, l16 = lane & 15;
    h8 b[4][KS];
#pragma unroll
    for (int ct = 0; ct < 4; ct++)
#pragma unroll
        for (int ks = 0; ks < KS; ks++)
#pragma unroll
            for (int j = 0; j < 8; j++)
                b[ct][ks][j] = (_Float16)W[(ks * 32 + quad * 8 + j) * HID + ct * 16 + l16];
    int ntile = n >> 4;
    int wpb = blockDim.x >> 6;
    int stride = gridDim.x * wpb;
    for (int rt = blockIdx.x * wpb + wave; rt < ntile; rt += stride) {
        int row0 = rt << 4;
        f4 acc[4];
#pragma unroll
        for (int ct = 0; ct < 4; ct++) acc[ct] = (f4)(0.f);
#pragma unroll
        for (int ks = 0; ks < KS; ks++) {
            h8 a;
            if constexpr (SIN) {
                // k-range [ks*32+quad*8, +8) lives in slice (ks*2 + (quad>>1)),
                // at col offset (quad&1)*8 of row (row0+l16): one 16 B load.
                a = *(const h8*)(X + (size_t)(ks * 2 + (quad >> 1)) * SLICE_E +
                                 (size_t)(row0 + l16) * 16 + (quad & 1) * 8);
            } else {
                const XT* xr = X + (size_t)(row0 + l16) * K + quad * 8 + ks * 32;
                float4 xa = *(const float4*)(xr);
                float4 xb = *(const float4*)(xr + 4);
                a[0] = (_Float16)xa.x; a[1] = (_Float16)xa.y;
                a[2] = (_Float16)xa.z; a[3] = (_Float16)xa.w;
                a[4] = (_Float16)xb.x; a[5] = (_Float16)xb.y;
                a[6] = (_Float16)xb.z; a[7] = (_Float16)xb.w;
            }
#pragma unroll
            for (int ct = 0; ct < 4; ct++)
                acc[ct] = __builtin_amdgcn_mfma_f32_16x16x32_f16(a, b[ct][ks], acc[ct], 0, 0, 0);
        }
        int r0 = row0 + quad * 4;
        float4 dv = *(const float4*)(dis + r0);
        float dd[4] = {dv.x, dv.y, dv.z, dv.w};
#pragma unroll
        for (int reg = 0; reg < 4; reg++) {
            // column block ct*16 + l16 -> slice ct, col l16
#pragma unroll
            for (int ct = 0; ct < 4; ct++)
                out[(size_t)ct * SLICE_E + (size_t)(r0 + reg) * 16 + l16] =
                    __float2half(dd[reg] * acc[ct][reg]);
        }
    }
}

// Sliced aggregate: out = relu(dis .* (tmp_self + gather-sum) + bias), one 16-col slice
// per block, slice = blockIdx&3. Under the empirical bid%8->XCD round-robin, each XCD
// touches exactly ONE 3.2 MB slice -> gather working set fits its 4 MiB L2 (vs 12.8 MB
// before: ~600K re-fetched lines/layer -> ~200K compulsory). 64 lanes = 8 rows x 8 lanes;
// per 8-edge group each lane handles one edge fully: 1 idx load + 2x16B gathers (12
// lane-loads/edge/layer vs aggregate4's 20). Per-row 8-lane compacting butterfly (all
// compile-time register indices) yields each lane's final col-pair c(m).
template <typename OutT>
__global__ __launch_bounds__(256) void aggregate_slice(const __half* __restrict__ tmp,
                                                       const float* __restrict__ dis,
                                                       const int* __restrict__ row_ptr,
                                                       const unsigned* __restrict__ cne,
                                                       const float* __restrict__ bias,
                                                       OutT* __restrict__ out, int n) {
    int wave = threadIdx.x >> 6, lane = threadIdx.x & 63;
    int m = lane & 7, rq = lane >> 3;
    int slice = blockIdx.x & 3;
    const char* tb = (const char*)(tmp + (size_t)slice * SLICE_E);
    int c = 8 * (m & 1) + 4 * ((m >> 1) & 1) + 2 * ((m >> 2) & 1);   // col pair after butterfly
    float2 blv = *(const float2*)(bias + slice * 16 + c);
    int sblk = blockIdx.x >> 2;          // index among same-slice blocks
    int nspb = gridDim.x >> 2;           // blocks per slice
    int ntasks = (n + 7) >> 3;           // 8 rows per task
    for (int task = sblk * 4 + wave; task < ntasks; task += nspb * 4) {
        int row = task * 8 + rq;
        float a[16];
#pragma unroll
        for (int i = 0; i < 16; i++) a[i] = 0.f;
        int sE = row_ptr[row];
        int ng = (row_ptr[row + 1] - sE) >> 3;
        const unsigned* ci = cne + sE + m;
        unsigned off = (ng > 0) ? ci[0] : 0u;
        for (int g = 0; g < ng; g++) {
            uint4 q0 = *(const uint4*)(tb + off);
            uint4 q1 = *(const uint4*)(tb + off + 16);
            if (g + 1 < ng) off = ci[(g + 1) * 8];
            float2 f;
            f = u2f2(q0.x); a[0] += f.x;  a[1] += f.y;
            f = u2f2(q0.y); a[2] += f.x;  a[3] += f.y;
            f = u2f2(q0.z); a[4] += f.x;  a[5] += f.y;
            f = u2f2(q0.w); a[6] += f.x;  a[7] += f.y;
            f = u2f2(q1.x); a[8] += f.x;  a[9] += f.y;
            f = u2f2(q1.y); a[10] += f.x; a[11] += f.y;
            f = u2f2(q1.z); a[12] += f.x; a[13] += f.y;
            f = u2f2(q1.w); a[14] += f.x; a[15] += f.y;
        }
        // compacting butterfly across the 8 lanes of this row (lanes share rq; xor 1/2/4
        // stays inside the 8-lane group). Lane keeps half, partner's half arrives via shfl.
        float v8[8], v4[4], v2[2];
#pragma unroll
        for (int i = 0; i < 8; i++) {
            float keep = (m & 1) ? a[i + 8] : a[i];
            float send = (m & 1) ? a[i] : a[i + 8];
            v8[i] = keep + __shfl_xor(send, 1);
        }
#pragma unroll
        for (int i = 0; i < 4; i++) {
            float keep = (m & 2) ? v8[i + 4] : v8[i];
            float send = (m & 2) ? v8[i] : v8[i + 4];
            v4[i] = keep + __shfl_xor(send, 2);
        }
#pragma unroll
        for (int i = 0; i < 2; i++) {
            float keep = (m & 4) ? v4[i + 2] : v4[i];
            float send = (m & 4) ? v4[i] : v4[i + 2];
            v2[i] = keep + __shfl_xor(send, 4);
        }
        float dr = dis[row];
        float2 sf = u2f2(*(const unsigned*)(tb + (size_t)row * 32 + 2 * c));
        float vx = fmaxf(dr * (sf.x + v2[0]) + blv.x, 0.f);
        float vy = fmaxf(dr * (sf.y + v2[1]) + blv.y, 0.f);
        if constexpr (__is_same(OutT, __half)) {
            *(__half2*)(out + (size_t)slice * SLICE_E + (size_t)row * 16 + c) =
                __floats2half2_rn(vx, vy);
        } else {
            *(float2*)(out + (size_t)slice * SLICE_E + (size_t)row * 16 + c) =
                make_float2(vx, vy);
        }
    }
}

__global__ __launch_bounds__(256) void pool_kernel(const float* __restrict__ h,
                                                   const int* __restrict__ batch,
                                                   const float* __restrict__ Wout,
                                                   const float* __restrict__ bout,
                                                   float* __restrict__ d_out, int n) {
    __shared__ float ssum[4][64];
    __shared__ float smax[4][64];
    int g = blockIdx.x;
    int wave = threadIdx.x >> 6, j = threadIdx.x & 63;
    size_t cbase = (size_t)(j >> 4) * SLICE_E + (j & 15);   // sliced float layout
    int lo = 0, hi = n;
    while (lo < hi) { int mid = (lo + hi) >> 1; if (batch[mid] < g) lo = mid + 1; else hi = mid; }
    int start = lo;
    hi = n;
    while (lo < hi) { int mid = (lo + hi) >> 1; if (batch[mid] < g + 1) lo = mid + 1; else hi = mid; }
    int end = lo;

    float sum = 0.f, mx = 0.f;
    for (int i = start + wave; i < end; i += 4) {
        float v = h[cbase + (size_t)i * 16];
        sum += v;
        mx = fmaxf(mx, v);
    }
    ssum[wave][j] = sum;
    smax[wave][j] = mx;
    __syncthreads();
    if (wave == 0) {
        sum = (ssum[0][j] + ssum[1][j]) + (ssum[2][j] + ssum[3][j]);
        mx = fmaxf(fmaxf(smax[0][j], smax[1][j]), fmaxf(smax[2][j], smax[3][j]));
        float cnt = (float)(end - start);
        float mean = sum / fmaxf(cnt, 1.f);
        float* pooled = d_out + NUM_GRAPHS;
        pooled[(size_t)g * (2 * HID) + j] = mean;
        pooled[(size_t)g * (2 * HID) + HID + j] = mx;
        float c = mean * Wout[j] + mx * Wout[HID + j];
#pragma unroll
        for (int off = 32; off; off >>= 1) c += __shfl_down(c, off);
        if (j == 0) d_out[g] = c + bout[0];
    }
}

// ---------------- launch ----------------

extern "C" void kernel_launch(void* const* d_in, const int* in_sizes, int n_in,
                              void* d_out, int out_size, void* d_ws, size_t ws_size,
                              hipStream_t stream) {
    const float* x    = (const float*)d_in[0];
    const int*   edge = (const int*)d_in[1];
    const int*   batch= (const int*)d_in[2];
    const float* W1 = (const float*)d_in[3];  const float* b1 = (const float*)d_in[4];
    const float* W2 = (const float*)d_in[5];  const float* b2 = (const float*)d_in[6];
    const float* W3 = (const float*)d_in[7];  const float* b3 = (const float*)d_in[8];
    const float* W4 = (const float*)d_in[9];  const float* b4 = (const float*)d_in[10];
    const float* Wout = (const float*)d_in[11]; const float* bout = (const float*)d_in[12];
    float* out = (float*)d_out;

    const int N = N_NODES;
    const int E = in_sizes[1] / 2;
    const int* src = edge;
    const int* dst = edge + E;
    const int chunk = (E + NCHUNK - 1) / NCHUNK;

    char* p = (char*)d_ws;
    auto alloc = [&](size_t bytes) -> char* {
        char* r = p;
        p += (bytes + 255) & ~(size_t)255;
        return r;
    };
    int*      pdeg     = (int*)alloc((size_t)N * 4);
    int*      row_ptr  = (int*)alloc((size_t)(N + 1) * 4);
    int*      partial  = (int*)alloc((size_t)TOTP * 4);
    int*      pincl    = (int*)alloc((size_t)TOTP * 4);
    int*      pbase    = (int*)alloc((size_t)TOTP * 4);
    int*      part_off = (int*)alloc((size_t)(NBUCK + 1) * 4);
    unsigned* part     = (unsigned*)alloc((size_t)1600000 * 4);
    unsigned* cne      = (unsigned*)alloc((size_t)CNE_MAX * 4);
    float*    dis      = (float*)alloc((size_t)N * 4);
    int*      bsum     = (int*)alloc(256 * 4);
    __half*   tmp      = (__half*)alloc(SLICE_E * 4 * 2);          // 4 half slices
    float*    hA       = (float*)alloc(SLICE_E * 4 * 4);           // 4 float slices
    __half*   hH       = (__half*)hA;   // fp16 h (sliced) aliases hA (hA dead until agg4)

    hist_partial<<<NCHUNK, 256, 0, stream>>>(dst, partial, E, chunk, (unsigned*)tmp);
    int nbp = (TOTP + 1023) / 1024;   // 196
    scan1<<<nbp, 256, 0, stream>>>(partial, pincl, bsum, TOTP, 0);
    scan3p<<<(TOTP + 255) / 256, 256, 0, stream>>>(partial, pincl, bsum, nbp, pbase, part_off, E);
    partition_edges<<<NCHUNK, 256, 0, stream>>>(src, dst, pbase, part, E, chunk);
    deg_dis<<<NBUCK, 256, 0, stream>>>(part, part_off, pdeg, dis, N);

    int nb = (N + 1023) / 1024;   // 98
    scan1<<<nb, 256, 0, stream>>>(pdeg, row_ptr + 1, bsum, N, 1);
    scan3<<<(N + 255) / 256, 256, 0, stream>>>(row_ptr, bsum, nb, N);
    build_csr<<<NBUCK, 256, 0, stream>>>(part, part_off, row_ptr, cne, N);

    const int AGG_BLOCKS = 2048;   // multiple of 8: 512 blocks per slice, 2 XCDs per slice
    const int GEMM_BLOCKS = 1024;

    gemm_mfma<IN_DIM, float, false><<<GEMM_BLOCKS, 256, 0, stream>>>(x, W1, dis, tmp, N);
    aggregate_slice<__half><<<AGG_BLOCKS, 256, 0, stream>>>(tmp, dis, row_ptr, cne, b1, hH, N);
    gemm_mfma<HID, _Float16, true><<<GEMM_BLOCKS, 256, 0, stream>>>((_Float16*)hH, W2, dis, tmp, N);
    aggregate_slice<__half><<<AGG_BLOCKS, 256, 0, stream>>>(tmp, dis, row_ptr, cne, b2, hH, N);
    gemm_mfma<HID, _Float16, true><<<GEMM_BLOCKS, 256, 0, stream>>>((_Float16*)hH, W3, dis, tmp, N);
    aggregate_slice<__half><<<AGG_BLOCKS, 256, 0, stream>>>(tmp, dis, row_ptr, cne, b3, hH, N);
    gemm_mfma<HID, _Float16, true><<<GEMM_BLOCKS, 256, 0, stream>>>((_Float16*)hH, W4, dis, tmp, N);
    aggregate_slice<float><<<AGG_BLOCKS, 256, 0, stream>>>(tmp, dis, row_ptr, cne, b4, hA, N);

    pool_kernel<<<NUM_GRAPHS, 256, 0, stream>>>(hA, batch, Wout, bout, out, N);
}

// Round 8
// 402.152 us; speedup vs baseline: 1.2546x; 1.0203x over previous
//
#include <hip/hip_runtime.h>
#include <hip/hip_fp16.h>

#define N_NODES 100000
#define IN_DIM 128
#define HID 64
#define NUM_GRAPHS 2048
#define CNE_MAX (1600000 + 7 * N_NODES)   // padded-to-8 CSR upper bound
#define BROWS 128                          // rows per bucket
#define NBUCK ((N_NODES + BROWS - 1) / BROWS)   // 782
#define NCHUNK 256                         // edge chunks (one block each)
#define TOTP (NBUCK * NCHUNK)              // 200192 partial counters
#define CAP 4096                           // LDS staging entries per bucket

typedef _Float16 h8 __attribute__((ext_vector_type(8)));
typedef float f4 __attribute__((ext_vector_type(4)));

// h/tmp live in 4 column-slices of 16 cols: [slice][(N+1) rows][16]. One slice = 3.2 MB
// (fits a 4 MiB per-XCD L2). SLICE_E = elements per slice (same count for half and float).
#define SLICE_E ((size_t)(N_NODES + 1) * 16)

__device__ __forceinline__ float2 u2f2(unsigned u) {
    __half2 h = *reinterpret_cast<__half2*>(&u);
    return __half22float2(h);
}

// ---------------- build phase (LDS-bucketed, NO per-edge global atomics — round-6 showed
// direct global scatter costs 100+ MB of write-allocate traffic at 0.87 TB/s) ----------------

// also zeroes the pad row (row N, 32 B) of all 4 tmp slices (replaces a memset dispatch)
__global__ __launch_bounds__(256) void hist_partial(const int* __restrict__ dst,
                                                    int* __restrict__ partial,
                                                    int E, int chunk,
                                                    unsigned* __restrict__ tmppad) {
    __shared__ int lh[NBUCK];
    int t = threadIdx.x, c = blockIdx.x;
    if (c == 0 && t < 32)
        tmppad[(size_t)(t >> 3) * ((N_NODES + 1) * 8) + (size_t)N_NODES * 8 + (t & 7)] = 0;
    for (int b = t; b < NBUCK; b += 256) lh[b] = 0;
    __syncthreads();
    int lo = c * chunk, hi = min(lo + chunk, E);
    for (int i = lo + t; i < hi; i += 256) atomicAdd(&lh[dst[i] >> 7], 1);
    __syncthreads();
    for (int b = t; b < NBUCK; b += 256) partial[b * NCHUNK + c] = lh[b];
}

// phase 1: per-block (1024 elems) inclusive scan + block sums; pad8 applied when flagged
__global__ void scan1(const int* __restrict__ counts, int* __restrict__ out1,
                      int* __restrict__ bsum, int n, int pad8) {
    __shared__ int s[256];
    int t = threadIdx.x;
    int base = blockIdx.x * 1024 + t * 4;
    int v[4];
#pragma unroll
    for (int i = 0; i < 4; i++) {
        int c = (base + i < n) ? counts[base + i] : 0;
        v[i] = pad8 ? ((c + 7) & ~7) : c;
    }
    int tsum = v[0] + v[1] + v[2] + v[3];
    s[t] = tsum;
    __syncthreads();
    for (int off = 1; off < 256; off <<= 1) {
        int tv = (t >= off) ? s[t - off] : 0;
        __syncthreads();
        s[t] += tv;
        __syncthreads();
    }
    int excl = s[t] - tsum;
    if (t == 255) bsum[blockIdx.x] = s[255];
    int run = excl;
#pragma unroll
    for (int i = 0; i < 4; i++) {
        run += v[i];
        if (base + i < n) out1[base + i] = run;
    }
}

// scan of block sums (nb <= 256) done redundantly per block in LDS (removes scan2 dispatch)
__device__ __forceinline__ void inline_bscan(const int* __restrict__ bsum, int nb, int* s) {
    int t = threadIdx.x;
    int v = (t < nb) ? bsum[t] : 0;
    s[t] = v;
    __syncthreads();
    for (int off = 1; off < 256; off <<= 1) {
        int tv = (t >= off) ? s[t - off] : 0;
        __syncthreads();
        s[t] += tv;
        __syncthreads();
    }
    int excl = s[t] - v;
    __syncthreads();
    s[t] = excl;
    __syncthreads();
}

__global__ __launch_bounds__(256) void scan3(int* __restrict__ row_ptr,
                                             const int* __restrict__ bsum, int nb, int n) {
    __shared__ int s[256];
    inline_bscan(bsum, nb, s);
    int i = blockIdx.x * blockDim.x + threadIdx.x;
    if (i == 0) row_ptr[0] = 0;
    if (i < n) row_ptr[i + 1] += s[i >> 10];
}

__global__ __launch_bounds__(256) void scan3p(const int* __restrict__ partial,
                                              const int* __restrict__ pincl,
                                              const int* __restrict__ bsum, int nb,
                                              int* __restrict__ base,
                                              int* __restrict__ part_off, int E) {
    __shared__ int s[256];
    inline_bscan(bsum, nb, s);
    int i = blockIdx.x * blockDim.x + threadIdx.x;
    if (i < TOTP) {
        int v = pincl[i] + s[i >> 10] - partial[i];
        base[i] = v;
        if ((i & (NCHUNK - 1)) == 0) part_off[i / NCHUNK] = v;
    }
    if (i == 0) part_off[NBUCK] = E;
}

__global__ __launch_bounds__(256) void partition_edges(const int* __restrict__ src,
                                                       const int* __restrict__ dst,
                                                       const int* __restrict__ base,
                                                       unsigned* __restrict__ part,
                                                       int E, int chunk) {
    __shared__ int cur[NBUCK];
    int t = threadIdx.x, c = blockIdx.x;
    for (int b = t; b < NBUCK; b += 256) cur[b] = base[b * NCHUNK + c];
    __syncthreads();
    int lo = c * chunk, hi = min(lo + chunk, E);
    for (int i = lo + t; i < hi; i += 256) {
        int s = src[i], d = dst[i];
        int pos = atomicAdd(&cur[d >> 7], 1);
        part[pos] = (unsigned)s | ((unsigned)(d & (BROWS - 1)) << 17);
    }
}

__global__ __launch_bounds__(256) void deg_dis(const unsigned* __restrict__ part,
                                               const int* __restrict__ part_off,
                                               int* __restrict__ pdeg,
                                               float* __restrict__ dis, int n) {
    __shared__ int cnt[BROWS];
    int t = threadIdx.x, b = blockIdx.x;
    int r0 = b * BROWS;
    if (t < BROWS) cnt[t] = 0;
    __syncthreads();
    for (int i = part_off[b] + t; i < part_off[b + 1]; i += 256)
        atomicAdd(&cnt[part[i] >> 17], 1);
    __syncthreads();
    int nrows = min(BROWS, n - r0);
    if (t < nrows) {
        int dg = cnt[t];
        pdeg[r0 + t] = dg;                          // raw; scan1 applies pad8
        dis[r0 + t] = rsqrtf((float)(dg + 1));
    }
}

// cne holds SLICE-LOCAL BYTE offsets (src * 32); pad slots -> N_NODES*32 (zero row).
__global__ __launch_bounds__(256) void build_csr(const unsigned* __restrict__ part,
                                                 const int* __restrict__ part_off,
                                                 const int* __restrict__ row_ptr,
                                                 unsigned* __restrict__ cne, int n) {
    __shared__ int fill[BROWS];
    __shared__ unsigned stage[CAP];
    int b = blockIdx.x;
    int r0 = b * BROWS;
    int t = threadIdx.x;
    int nrows = min(BROWS, n - r0);
    int base = row_ptr[r0];
    int region = row_ptr[r0 + nrows] - base;
    for (int r = t; r < nrows; r += 256) fill[r] = row_ptr[r0 + r] - base;
    int i0 = part_off[b], i1 = part_off[b + 1];
    if (region <= CAP) {
        for (int i = t; i < region; i += 256) stage[i] = (unsigned)N_NODES << 5;
        __syncthreads();
        for (int i = i0 + t; i < i1; i += 256) {
            unsigned pe = part[i];
            int pos = atomicAdd(&fill[pe >> 17], 1);
            stage[pos] = (pe & 0x1FFFFu) << 5;
        }
        __syncthreads();
        for (int i = t; i < region; i += 256) cne[base + i] = stage[i];
    } else {
        for (int i = t; i < region; i += 256) cne[base + i] = (unsigned)N_NODES << 5;
        __syncthreads();
        for (int i = i0 + t; i < i1; i += 256) {
            unsigned pe = part[i];
            int pos = atomicAdd(&fill[pe >> 17], 1);
            cne[base + pos] = (pe & 0x1FFFFu) << 5;
        }
    }
}

// ---------------- per-layer compute ----------------

// MFMA GEMM: out[row][col] = (half) dis[row] * sum_k X[row][k] * W[k][col]
// SIN: X is in sliced-half layout; else X is row-major float (layer 1).
// Output always sliced-half. Same MFMA path / rounding points as verified kernel.
template <int K, typename XT, bool SIN>
__global__ __launch_bounds__(256) void gemm_mfma(const XT* __restrict__ X,
                                                 const float* __restrict__ W,
                                                 const float* __restrict__ dis,
                                                 __half* __restrict__ out, int n) {
    const int KS = K / 32;
    int wave = threadIdx.x >> 6, lane = threadIdx.x & 63;
    int quad = lane >> 4, l16 = lane & 15;
    h8 b[4][KS];
#pragma unroll
    for (int ct = 0; ct < 4; ct++)
#pragma unroll
        for (int ks = 0; ks < KS; ks++)
#pragma unroll
            for (int j = 0; j < 8; j++)
                b[ct][ks][j] = (_Float16)W[(ks * 32 + quad * 8 + j) * HID + ct * 16 + l16];
    int ntile = n >> 4;
    int wpb = blockDim.x >> 6;
    int stride = gridDim.x * wpb;
    for (int rt = blockIdx.x * wpb + wave; rt < ntile; rt += stride) {
        int row0 = rt << 4;
        f4 acc[4];
#pragma unroll
        for (int ct = 0; ct < 4; ct++) acc[ct] = (f4)(0.f);
#pragma unroll
        for (int ks = 0; ks < KS; ks++) {
            h8 a;
            if constexpr (SIN) {
                // k-range [ks*32+quad*8, +8) lives in slice (ks*2 + (quad>>1)),
                // at col offset (quad&1)*8 of row (row0+l16): one 16 B load.
                a = *(const h8*)(X + (size_t)(ks * 2 + (quad >> 1)) * SLICE_E +
                                 (size_t)(row0 + l16) * 16 + (quad & 1) * 8);
            } else {
                const XT* xr = X + (size_t)(row0 + l16) * K + quad * 8 + ks * 32;
                float4 xa = *(const float4*)(xr);
                float4 xb = *(const float4*)(xr + 4);
                a[0] = (_Float16)xa.x; a[1] = (_Float16)xa.y;
                a[2] = (_Float16)xa.z; a[3] = (_Float16)xa.w;
                a[4] = (_Float16)xb.x; a[5] = (_Float16)xb.y;
                a[6] = (_Float16)xb.z; a[7] = (_Float16)xb.w;
            }
#pragma unroll
            for (int ct = 0; ct < 4; ct++)
                acc[ct] = __builtin_amdgcn_mfma_f32_16x16x32_f16(a, b[ct][ks], acc[ct], 0, 0, 0);
        }
        int r0 = row0 + quad * 4;
        float4 dv = *(const float4*)(dis + r0);
        float dd[4] = {dv.x, dv.y, dv.z, dv.w};
#pragma unroll
        for (int reg = 0; reg < 4; reg++) {
            // column block ct*16 + l16 -> slice ct, col l16
#pragma unroll
            for (int ct = 0; ct < 4; ct++)
                out[(size_t)ct * SLICE_E + (size_t)(r0 + reg) * 16 + l16] =
                    __float2half(dd[reg] * acc[ct][reg]);
        }
    }
}

// Sliced aggregate, aggregate4-structured: out = relu(dis .* (self + gather-sum) + bias),
// one 16-col slice per block (slice = blockIdx&3 -> under bid%8->XCD round-robin each XCD
// touches ONE 3.2MB slice: gathers are L2-hits, round-7 FETCH 43MB confirms). 64 lanes =
// 16 rows (rq) x 4 col-quads (m2, 8B): lane processes ALL 8 edges of its row's group (8
// gathers in flight + 8 prefetched = aggregate4's MLP, which round-7's 2-deep lost). idx
// uint4s broadcast across the row's 4 lanes. Lane's 4 cols are final - no cross-lane reduce.
template <typename OutT>
__global__ __launch_bounds__(256) void aggregate_slice(const __half* __restrict__ tmp,
                                                       const float* __restrict__ dis,
                                                       const int* __restrict__ row_ptr,
                                                       const unsigned* __restrict__ cne,
                                                       const float* __restrict__ bias,
                                                       OutT* __restrict__ out, int n) {
    int wave = threadIdx.x >> 6, lane = threadIdx.x & 63;
    int m2 = lane & 3, rq = lane >> 2;     // col-quad (8B), row 0..15
    int slice = blockIdx.x & 3;
    const char* tb = (const char*)(tmp + (size_t)slice * SLICE_E) + 8 * m2;
    float4 blv = *(const float4*)(bias + slice * 16 + 4 * m2);
    int sblk = blockIdx.x >> 2;            // index among same-slice blocks
    int nspb = gridDim.x >> 2;             // blocks per slice
    int ntask = n >> 4;                    // 16 rows per task (100000/16 = 6250)
    const unsigned Z = (unsigned)N_NODES << 5;
    for (int task = sblk * 4 + wave; task < ntask; task += nspb * 4) {
        int row = (task << 4) + rq;
        float dr = dis[row];
        int sE = row_ptr[row], eE = row_ptr[row + 1];
        int ng = (eE - sE) >> 3;
        const uint4* ip = (const uint4*)(cne + sE);
        uint4 A0, A1;
        if (ng > 0) { A0 = ip[0]; A1 = ip[1]; }
        else { A0 = make_uint4(Z, Z, Z, Z); A1 = make_uint4(Z, Z, Z, Z); }
        uint2 g0 = *(const uint2*)(tb + A0.x);
        uint2 g1 = *(const uint2*)(tb + A0.y);
        uint2 g2 = *(const uint2*)(tb + A0.z);
        uint2 g3 = *(const uint2*)(tb + A0.w);
        uint2 g4 = *(const uint2*)(tb + A1.x);
        uint2 g5 = *(const uint2*)(tb + A1.y);
        uint2 g6 = *(const uint2*)(tb + A1.z);
        uint2 g7 = *(const uint2*)(tb + A1.w);
        float a0 = 0.f, a1 = 0.f, a2 = 0.f, a3 = 0.f;
        uint4 B0, B1;
        if (ng > 1) { B0 = ip[2]; B1 = ip[3]; }
        for (int g = 1; g < ng; g++) {
            uint2 u0 = *(const uint2*)(tb + B0.x);
            uint2 u1 = *(const uint2*)(tb + B0.y);
            uint2 u2 = *(const uint2*)(tb + B0.z);
            uint2 u3 = *(const uint2*)(tb + B0.w);
            uint2 u4 = *(const uint2*)(tb + B1.x);
            uint2 u5 = *(const uint2*)(tb + B1.y);
            uint2 u6 = *(const uint2*)(tb + B1.z);
            uint2 u7 = *(const uint2*)(tb + B1.w);
            if (g + 1 < ng) { B0 = ip[2 * g + 2]; B1 = ip[2 * g + 3]; }
            float2 f;
            f = u2f2(g0.x); a0 += f.x; a1 += f.y; f = u2f2(g0.y); a2 += f.x; a3 += f.y;
            f = u2f2(g1.x); a0 += f.x; a1 += f.y; f = u2f2(g1.y); a2 += f.x; a3 += f.y;
            f = u2f2(g2.x); a0 += f.x; a1 += f.y; f = u2f2(g2.y); a2 += f.x; a3 += f.y;
            f = u2f2(g3.x); a0 += f.x; a1 += f.y; f = u2f2(g3.y); a2 += f.x; a3 += f.y;
            f = u2f2(g4.x); a0 += f.x; a1 += f.y; f = u2f2(g4.y); a2 += f.x; a3 += f.y;
            f = u2f2(g5.x); a0 += f.x; a1 += f.y; f = u2f2(g5.y); a2 += f.x; a3 += f.y;
            f = u2f2(g6.x); a0 += f.x; a1 += f.y; f = u2f2(g6.y); a2 += f.x; a3 += f.y;
            f = u2f2(g7.x); a0 += f.x; a1 += f.y; f = u2f2(g7.y); a2 += f.x; a3 += f.y;
            g0 = u0; g1 = u1; g2 = u2; g3 = u3;
            g4 = u4; g5 = u5; g6 = u6; g7 = u7;
        }
        {
            float2 f;
            f = u2f2(g0.x); a0 += f.x; a1 += f.y; f = u2f2(g0.y); a2 += f.x; a3 += f.y;
            f = u2f2(g1.x); a0 += f.x; a1 += f.y; f = u2f2(g1.y); a2 += f.x; a3 += f.y;
            f = u2f2(g2.x); a0 += f.x; a1 += f.y; f = u2f2(g2.y); a2 += f.x; a3 += f.y;
            f = u2f2(g3.x); a0 += f.x; a1 += f.y; f = u2f2(g3.y); a2 += f.x; a3 += f.y;
            f = u2f2(g4.x); a0 += f.x; a1 += f.y; f = u2f2(g4.y); a2 += f.x; a3 += f.y;
            f = u2f2(g5.x); a0 += f.x; a1 += f.y; f = u2f2(g5.y); a2 += f.x; a3 += f.y;
            f = u2f2(g6.x); a0 += f.x; a1 += f.y; f = u2f2(g6.y); a2 += f.x; a3 += f.y;
            f = u2f2(g7.x); a0 += f.x; a1 += f.y; f = u2f2(g7.y); a2 += f.x; a3 += f.y;
        }
        uint2 sv = *(const uint2*)(tb + (size_t)row * 32);
        float2 s01 = u2f2(sv.x), s23 = u2f2(sv.y);
        float v0 = fmaxf(dr * (s01.x + a0) + blv.x, 0.f);
        float v1 = fmaxf(dr * (s01.y + a1) + blv.y, 0.f);
        float v2 = fmaxf(dr * (s23.x + a2) + blv.z, 0.f);
        float v3 = fmaxf(dr * (s23.y + a3) + blv.w, 0.f);
        if constexpr (__is_same(OutT, __half)) {
            __half2 p01 = __floats2half2_rn(v0, v1);
            __half2 p23 = __floats2half2_rn(v2, v3);
            *(uint2*)(out + (size_t)slice * SLICE_E + (size_t)row * 16 + 4 * m2) =
                make_uint2(*(unsigned*)&p01, *(unsigned*)&p23);
        } else {
            *(float4*)(out + (size_t)slice * SLICE_E + (size_t)row * 16 + 4 * m2) =
                make_float4(v0, v1, v2, v3);
        }
    }
}

__global__ __launch_bounds__(256) void pool_kernel(const float* __restrict__ h,
                                                   const int* __restrict__ batch,
                                                   const float* __restrict__ Wout,
                                                   const float* __restrict__ bout,
                                                   float* __restrict__ d_out, int n) {
    __shared__ float ssum[4][64];
    __shared__ float smax[4][64];
    int g = blockIdx.x;
    int wave = threadIdx.x >> 6, j = threadIdx.x & 63;
    size_t cbase = (size_t)(j >> 4) * SLICE_E + (j & 15);   // sliced float layout
    int lo = 0, hi = n;
    while (lo < hi) { int mid = (lo + hi) >> 1; if (batch[mid] < g) lo = mid + 1; else hi = mid; }
    int start = lo;
    hi = n;
    while (lo < hi) { int mid = (lo + hi) >> 1; if (batch[mid] < g + 1) lo = mid + 1; else hi = mid; }
    int end = lo;

    float sum = 0.f, mx = 0.f;
    for (int i = start + wave; i < end; i += 4) {
        float v = h[cbase + (size_t)i * 16];
        sum += v;
        mx = fmaxf(mx, v);
    }
    ssum[wave][j] = sum;
    smax[wave][j] = mx;
    __syncthreads();
    if (wave == 0) {
        sum = (ssum[0][j] + ssum[1][j]) + (ssum[2][j] + ssum[3][j]);
        mx = fmaxf(fmaxf(smax[0][j], smax[1][j]), fmaxf(smax[2][j], smax[3][j]));
        float cnt = (float)(end - start);
        float mean = sum / fmaxf(cnt, 1.f);
        float* pooled = d_out + NUM_GRAPHS;
        pooled[(size_t)g * (2 * HID) + j] = mean;
        pooled[(size_t)g * (2 * HID) + HID + j] = mx;
        float c = mean * Wout[j] + mx * Wout[HID + j];
#pragma unroll
        for (int off = 32; off; off >>= 1) c += __shfl_down(c, off);
        if (j == 0) d_out[g] = c + bout[0];
    }
}

// ---------------- launch ----------------

extern "C" void kernel_launch(void* const* d_in, const int* in_sizes, int n_in,
                              void* d_out, int out_size, void* d_ws, size_t ws_size,
                              hipStream_t stream) {
    const float* x    = (const float*)d_in[0];
    const int*   edge = (const int*)d_in[1];
    const int*   batch= (const int*)d_in[2];
    const float* W1 = (const float*)d_in[3];  const float* b1 = (const float*)d_in[4];
    const float* W2 = (const float*)d_in[5];  const float* b2 = (const float*)d_in[6];
    const float* W3 = (const float*)d_in[7];  const float* b3 = (const float*)d_in[8];
    const float* W4 = (const float*)d_in[9];  const float* b4 = (const float*)d_in[10];
    const float* Wout = (const float*)d_in[11]; const float* bout = (const float*)d_in[12];
    float* out = (float*)d_out;

    const int N = N_NODES;
    const int E = in_sizes[1] / 2;
    const int* src = edge;
    const int* dst = edge + E;
    const int chunk = (E + NCHUNK - 1) / NCHUNK;

    char* p = (char*)d_ws;
    auto alloc = [&](size_t bytes) -> char* {
        char* r = p;
        p += (bytes + 255) & ~(size_t)255;
        return r;
    };
    int*      pdeg     = (int*)alloc((size_t)N * 4);
    int*      row_ptr  = (int*)alloc((size_t)(N + 1) * 4);
    int*      partial  = (int*)alloc((size_t)TOTP * 4);
    int*      pincl    = (int*)alloc((size_t)TOTP * 4);
    int*      pbase    = (int*)alloc((size_t)TOTP * 4);
    int*      part_off = (int*)alloc((size_t)(NBUCK + 1) * 4);
    unsigned* part     = (unsigned*)alloc((size_t)1600000 * 4);
    unsigned* cne      = (unsigned*)alloc((size_t)CNE_MAX * 4);
    float*    dis      = (float*)alloc((size_t)N * 4);
    int*      bsum     = (int*)alloc(256 * 4);
    __half*   tmp      = (__half*)alloc(SLICE_E * 4 * 2);          // 4 half slices
    float*    hA       = (float*)alloc(SLICE_E * 4 * 4);           // 4 float slices
    __half*   hH       = (__half*)hA;   // fp16 h (sliced) aliases hA (hA dead until agg4)

    hist_partial<<<NCHUNK, 256, 0, stream>>>(dst, partial, E, chunk, (unsigned*)tmp);
    int nbp = (TOTP + 1023) / 1024;   // 196
    scan1<<<nbp, 256, 0, stream>>>(partial, pincl, bsum, TOTP, 0);
    scan3p<<<(TOTP + 255) / 256, 256, 0, stream>>>(partial, pincl, bsum, nbp, pbase, part_off, E);
    partition_edges<<<NCHUNK, 256, 0, stream>>>(src, dst, pbase, part, E, chunk);
    deg_dis<<<NBUCK, 256, 0, stream>>>(part, part_off, pdeg, dis, N);

    int nb = (N + 1023) / 1024;   // 98
    scan1<<<nb, 256, 0, stream>>>(pdeg, row_ptr + 1, bsum, N, 1);
    scan3<<<(N + 255) / 256, 256, 0, stream>>>(row_ptr, bsum, nb, N);
    build_csr<<<NBUCK, 256, 0, stream>>>(part, part_off, row_ptr, cne, N);

    const int AGG_BLOCKS = 2048;   // multiple of 8: 512 blocks per slice, 2 XCDs per slice
    const int GEMM_BLOCKS = 1024;

    gemm_mfma<IN_DIM, float, false><<<GEMM_BLOCKS, 256, 0, stream>>>(x, W1, dis, tmp, N);
    aggregate_slice<__half><<<AGG_BLOCKS, 256, 0, stream>>>(tmp, dis, row_ptr, cne, b1, hH, N);
    gemm_mfma<HID, _Float16, true><<<GEMM_BLOCKS, 256, 0, stream>>>((_Float16*)hH, W2, dis, tmp, N);
    aggregate_slice<__half><<<AGG_BLOCKS, 256, 0, stream>>>(tmp, dis, row_ptr, cne, b2, hH, N);
    gemm_mfma<HID, _Float16, true><<<GEMM_BLOCKS, 256, 0, stream>>>((_Float16*)hH, W3, dis, tmp, N);
    aggregate_slice<__half><<<AGG_BLOCKS, 256, 0, stream>>>(tmp, dis, row_ptr, cne, b3, hH, N);
    gemm_mfma<HID, _Float16, true><<<GEMM_BLOCKS, 256, 0, stream>>>((_Float16*)hH, W4, dis, tmp, N);
    aggregate_slice<float><<<AGG_BLOCKS, 256, 0, stream>>>(tmp, dis, row_ptr, cne, b4, hA, N);

    pool_kernel<<<NUM_GRAPHS, 256, 0, stream>>>(hA, batch, Wout, bout, out, N);
}

// Round 10
// 353.782 us; speedup vs baseline: 1.4262x; 1.1367x over previous
//
#include <hip/hip_runtime.h>
#include <hip/hip_fp16.h>

#define N_NODES 100000
#define IN_DIM 128
#define HID 64
#define NUM_GRAPHS 2048
#define CNE_MAX (1600000 + 7 * N_NODES)   // padded-to-8 CSR upper bound
#define BROWS 128                          // rows per bucket
#define NBUCK ((N_NODES + BROWS - 1) / BROWS)   // 782
#define NCHUNK 256                         // edge chunks (one block each)
#define TOTP (NBUCK * NCHUNK)              // 200192 partial counters
#define CAP 4096                           // LDS staging entries per bucket

typedef _Float16 h8 __attribute__((ext_vector_type(8)));
typedef float f4 __attribute__((ext_vector_type(4)));
typedef unsigned u32x4 __attribute__((ext_vector_type(4)));   // clang vector: valid for
                                                              // __builtin_nontemporal_load
                                                              // (HIP uint4 class is NOT)

__device__ __forceinline__ float2 u2f2(unsigned u) {
    __half2 h = *reinterpret_cast<__half2*>(&u);
    return __half22float2(h);
}

// ---------------- build phase (LDS-bucketed, NO per-edge global atomics — round-6 measured
// the direct-atomic alternative at 3.5x worse: 100+ MB write-allocate at 0.87 TB/s) --------

// also zeroes the pad row (row N) of tmp (replaces a memset dispatch)
__global__ __launch_bounds__(256) void hist_partial(const int* __restrict__ dst,
                                                    int* __restrict__ partial,
                                                    int E, int chunk,
                                                    unsigned* __restrict__ padA,
                                                    unsigned* __restrict__ padB) {
    __shared__ int lh[NBUCK];
    int t = threadIdx.x, c = blockIdx.x;
    if (c == 0) {
        if (t < 32) padA[t] = 0;
        else if (t < 64) padB[t - 32] = 0;
    }
    for (int b = t; b < NBUCK; b += 256) lh[b] = 0;
    __syncthreads();
    int lo = c * chunk, hi = min(lo + chunk, E);
    for (int i = lo + t; i < hi; i += 256) atomicAdd(&lh[dst[i] >> 7], 1);
    __syncthreads();
    for (int b = t; b < NBUCK; b += 256) partial[b * NCHUNK + c] = lh[b];
}

// phase 1: per-block (1024 elems) inclusive scan + block sums; pad8 applied when flagged
__global__ void scan1(const int* __restrict__ counts, int* __restrict__ out1,
                      int* __restrict__ bsum, int n, int pad8) {
    __shared__ int s[256];
    int t = threadIdx.x;
    int base = blockIdx.x * 1024 + t * 4;
    int v[4];
#pragma unroll
    for (int i = 0; i < 4; i++) {
        int c = (base + i < n) ? counts[base + i] : 0;
        v[i] = pad8 ? ((c + 7) & ~7) : c;
    }
    int tsum = v[0] + v[1] + v[2] + v[3];
    s[t] = tsum;
    __syncthreads();
    for (int off = 1; off < 256; off <<= 1) {
        int tv = (t >= off) ? s[t - off] : 0;
        __syncthreads();
        s[t] += tv;
        __syncthreads();
    }
    int excl = s[t] - tsum;
    if (t == 255) bsum[blockIdx.x] = s[255];
    int run = excl;
#pragma unroll
    for (int i = 0; i < 4; i++) {
        run += v[i];
        if (base + i < n) out1[base + i] = run;
    }
}

// scan of block sums (nb <= 256) done redundantly per block in LDS (removes scan2 dispatch)
__device__ __forceinline__ void inline_bscan(const int* __restrict__ bsum, int nb, int* s) {
    int t = threadIdx.x;
    int v = (t < nb) ? bsum[t] : 0;
    s[t] = v;
    __syncthreads();
    for (int off = 1; off < 256; off <<= 1) {
        int tv = (t >= off) ? s[t - off] : 0;
        __syncthreads();
        s[t] += tv;
        __syncthreads();
    }
    int excl = s[t] - v;
    __syncthreads();
    s[t] = excl;
    __syncthreads();
}

__global__ __launch_bounds__(256) void scan3(int* __restrict__ row_ptr,
                                             const int* __restrict__ bsum, int nb, int n) {
    __shared__ int s[256];
    inline_bscan(bsum, nb, s);
    int i = blockIdx.x * blockDim.x + threadIdx.x;
    if (i == 0) row_ptr[0] = 0;
    if (i < n) row_ptr[i + 1] += s[i >> 10];
}

__global__ __launch_bounds__(256) void scan3p(const int* __restrict__ partial,
                                              const int* __restrict__ pincl,
                                              const int* __restrict__ bsum, int nb,
                                              int* __restrict__ base,
                                              int* __restrict__ part_off, int E) {
    __shared__ int s[256];
    inline_bscan(bsum, nb, s);
    int i = blockIdx.x * blockDim.x + threadIdx.x;
    if (i < TOTP) {
        int v = pincl[i] + s[i >> 10] - partial[i];
        base[i] = v;
        if ((i & (NCHUNK - 1)) == 0) part_off[i / NCHUNK] = v;
    }
    if (i == 0) part_off[NBUCK] = E;
}

__global__ __launch_bounds__(256) void partition_edges(const int* __restrict__ src,
                                                       const int* __restrict__ dst,
                                                       const int* __restrict__ base,
                                                       unsigned* __restrict__ part,
                                                       int E, int chunk) {
    __shared__ int cur[NBUCK];
    int t = threadIdx.x, c = blockIdx.x;
    for (int b = t; b < NBUCK; b += 256) cur[b] = base[b * NCHUNK + c];
    __syncthreads();
    int lo = c * chunk, hi = min(lo + chunk, E);
    for (int i = lo + t; i < hi; i += 256) {
        int s = src[i], d = dst[i];
        int pos = atomicAdd(&cur[d >> 7], 1);
        part[pos] = (unsigned)s | ((unsigned)(d & (BROWS - 1)) << 17);
    }
}

__global__ __launch_bounds__(256) void deg_dis(const unsigned* __restrict__ part,
                                               const int* __restrict__ part_off,
                                               int* __restrict__ pdeg,
                                               float* __restrict__ dis, int n) {
    __shared__ int cnt[BROWS];
    int t = threadIdx.x, b = blockIdx.x;
    int r0 = b * BROWS;
    if (t < BROWS) cnt[t] = 0;
    __syncthreads();
    for (int i = part_off[b] + t; i < part_off[b + 1]; i += 256)
        atomicAdd(&cnt[part[i] >> 17], 1);
    __syncthreads();
    int nrows = min(BROWS, n - r0);
    if (t < nrows) {
        int dg = cnt[t];
        pdeg[r0 + t] = dg;                          // raw; scan1 applies pad8
        dis[r0 + t] = rsqrtf((float)(dg + 1));
    }
}

// stage/cne hold BYTE offsets (src * 128); pad slots -> N_NODES*128 (zero row).
__global__ __launch_bounds__(256) void build_csr(const unsigned* __restrict__ part,
                                                 const int* __restrict__ part_off,
                                                 const int* __restrict__ row_ptr,
                                                 unsigned* __restrict__ cne, int n) {
    __shared__ int fill[BROWS];
    __shared__ unsigned stage[CAP];
    int b = blockIdx.x;
    int r0 = b * BROWS;
    int t = threadIdx.x;
    int nrows = min(BROWS, n - r0);
    int base = row_ptr[r0];
    int region = row_ptr[r0 + nrows] - base;
    for (int r = t; r < nrows; r += 256) fill[r] = row_ptr[r0 + r] - base;
    int i0 = part_off[b], i1 = part_off[b + 1];
    if (region <= CAP) {
        for (int i = t; i < region; i += 256) stage[i] = (unsigned)N_NODES << 7;
        __syncthreads();
        for (int i = i0 + t; i < i1; i += 256) {
            unsigned pe = part[i];
            int pos = atomicAdd(&fill[pe >> 17], 1);
            stage[pos] = (pe & 0x1FFFFu) << 7;
        }
        __syncthreads();
        for (int i = t; i < region; i += 256) cne[base + i] = stage[i];
    } else {
        for (int i = t; i < region; i += 256) cne[base + i] = (unsigned)N_NODES << 7;
        __syncthreads();
        for (int i = i0 + t; i < i1; i += 256) {
            unsigned pe = part[i];
            int pos = atomicAdd(&fill[pe >> 17], 1);
            cne[base + pos] = (pe & 0x1FFFFu) << 7;
        }
    }
}

// ---------------- per-layer compute ----------------

// MFMA GEMM: out[row][col] = (half) dis[row] * sum_k X[row][k] * W[k][col]
// XT = float (layer 1) or _Float16 (h from previous layer; A-frag = direct 16 B load).
template <int K, typename XT>
__global__ __launch_bounds__(256) void gemm_mfma(const XT* __restrict__ X,
                                                 const float* __restrict__ W,
                                                 const float* __restrict__ dis,
                                                 __half* __restrict__ out, int n) {
    const int KS = K / 32;
    int wave = threadIdx.x >> 6, lane = threadIdx.x & 63;
    int quad = lane >> 4, l16 = lane & 15;
    h8 b[4][KS];
#pragma unroll
    for (int ct = 0; ct < 4; ct++)
#pragma unroll
        for (int ks = 0; ks < KS; ks++)
#pragma unroll
            for (int j = 0; j < 8; j++)
                b[ct][ks][j] = (_Float16)W[(ks * 32 + quad * 8 + j) * HID + ct * 16 + l16];
    int ntile = n >> 4;
    int wpb = blockDim.x >> 6;
    int stride = gridDim.x * wpb;
    for (int rt = blockIdx.x * wpb + wave; rt < ntile; rt += stride) {
        int row0 = rt << 4;
        const XT* xr = X + (size_t)(row0 + l16) * K + quad * 8;
        f4 acc[4];
#pragma unroll
        for (int ct = 0; ct < 4; ct++) acc[ct] = (f4)(0.f);
#pragma unroll
        for (int ks = 0; ks < KS; ks++) {
            h8 a;
            if constexpr (__is_same(XT, float)) {
                float4 xa = *(const float4*)(xr + ks * 32);
                float4 xb = *(const float4*)(xr + ks * 32 + 4);
                a[0] = (_Float16)xa.x; a[1] = (_Float16)xa.y;
                a[2] = (_Float16)xa.z; a[3] = (_Float16)xa.w;
                a[4] = (_Float16)xb.x; a[5] = (_Float16)xb.y;
                a[6] = (_Float16)xb.z; a[7] = (_Float16)xb.w;
            } else {
                a = *(const h8*)(xr + ks * 32);
            }
#pragma unroll
            for (int ct = 0; ct < 4; ct++)
                acc[ct] = __builtin_amdgcn_mfma_f32_16x16x32_f16(a, b[ct][ks], acc[ct], 0, 0, 0);
        }
        int r0 = row0 + quad * 4;
        float4 dv = *(const float4*)(dis + r0);
        float dd[4] = {dv.x, dv.y, dv.z, dv.w};
#pragma unroll
        for (int reg = 0; reg < 4; reg++) {
            __half* orow = out + (size_t)(r0 + reg) * HID + l16;
            orow[0]  = __float2half(dd[reg] * acc[0][reg]);
            orow[16] = __float2half(dd[reg] * acc[1][reg]);
            orow[32] = __float2half(dd[reg] * acc[2][reg]);
            orow[48] = __float2half(dd[reg] * acc[3][reg]);
        }
    }
}

// out[row] = relu( dis[row] * (tmp[row] + sum_cols tmp[col]) + bias ); pads read zero row N.
// Dual-row lane layout: 64 lanes = 32 column-pairs (m) x 2 rows (hh): only 2 distinct
// random rows per VMEM instruction (the measured sweet spot: 2-4 rows/instr = 40 us/layer;
// 8-16 rows/instr (sliced variants) = 48-51 us despite halved FETCH). Lane owns row 2p+hh,
// processes all 8 edges per group: 2 idx loads + 8 gathers in flight (16 w/ depth-2
// prefetch). Idx stream loaded NON-TEMPORAL (via clang ext_vector u32x4 — HIP uint4 class
// is rejected by the builtin): 9.6 MB/layer sequential stream with zero reuse must not
// evict the 12.8 MB randomly-gathered tmp table out of L2.
template <typename OutT>
__global__ __launch_bounds__(256) void aggregate2(const __half* __restrict__ tmp,
                                                  const float* __restrict__ dis,
                                                  const int* __restrict__ row_ptr,
                                                  const unsigned* __restrict__ cne,
                                                  const float* __restrict__ bias,
                                                  OutT* __restrict__ out, int n) {
    int wave = threadIdx.x >> 6, lane = threadIdx.x & 63;
    int m = lane & 31, hh = lane >> 5;
    const char* tbase = (const char*)tmp + 4 * m;   // lane's column-pair byte base
    int wpb = blockDim.x >> 6;
    int stride = gridDim.x * wpb;
    float2 blv = *(const float2*)(bias + 2 * m);
    int npairs = n >> 1;
    for (int p = blockIdx.x * wpb + wave; p < npairs; p += stride) {
        int row = 2 * p + hh;
        float dr = dis[row];
        int s = row_ptr[row], e = row_ptr[row + 1];
        int ng = (e - s) >> 3;   // 8-edge groups (rows padded to 8)
        float ax0 = 0.f, ay0 = 0.f, ax1 = 0.f, ay1 = 0.f;
        float ax2 = 0.f, ay2 = 0.f, ax3 = 0.f, ay3 = 0.f;
        if (ng > 0) {
            const u32x4* ip = (const u32x4*)(cne + s);
            u32x4 A0 = __builtin_nontemporal_load(ip);
            u32x4 A1 = __builtin_nontemporal_load(ip + 1);
            __half2 g0 = *(const __half2*)(tbase + A0.x);
            __half2 g1 = *(const __half2*)(tbase + A0.y);
            __half2 g2 = *(const __half2*)(tbase + A0.z);
            __half2 g3 = *(const __half2*)(tbase + A0.w);
            __half2 g4 = *(const __half2*)(tbase + A1.x);
            __half2 g5 = *(const __half2*)(tbase + A1.y);
            __half2 g6 = *(const __half2*)(tbase + A1.z);
            __half2 g7 = *(const __half2*)(tbase + A1.w);
            u32x4 B0, B1;
            if (ng > 1) {
                B0 = __builtin_nontemporal_load(ip + 2);
                B1 = __builtin_nontemporal_load(ip + 3);
            }
            for (int g = 1; g < ng; g++) {
                __half2 u0 = *(const __half2*)(tbase + B0.x);
                __half2 u1 = *(const __half2*)(tbase + B0.y);
                __half2 u2 = *(const __half2*)(tbase + B0.z);
                __half2 u3 = *(const __half2*)(tbase + B0.w);
                __half2 u4 = *(const __half2*)(tbase + B1.x);
                __half2 u5 = *(const __half2*)(tbase + B1.y);
                __half2 u6 = *(const __half2*)(tbase + B1.z);
                __half2 u7 = *(const __half2*)(tbase + B1.w);
                if (g + 1 < ng) {
                    B0 = __builtin_nontemporal_load(ip + 2 * (g + 1));
                    B1 = __builtin_nontemporal_load(ip + 2 * (g + 1) + 1);
                }
                float2 f0 = __half22float2(g0), f1 = __half22float2(g1);
                float2 f2 = __half22float2(g2), f3 = __half22float2(g3);
                float2 f4_ = __half22float2(g4), f5 = __half22float2(g5);
                float2 f6 = __half22float2(g6), f7 = __half22float2(g7);
                ax0 += f0.x; ay0 += f0.y; ax1 += f1.x; ay1 += f1.y;
                ax2 += f2.x; ay2 += f2.y; ax3 += f3.x; ay3 += f3.y;
                ax0 += f4_.x; ay0 += f4_.y; ax1 += f5.x; ay1 += f5.y;
                ax2 += f6.x; ay2 += f6.y; ax3 += f7.x; ay3 += f7.y;
                g0 = u0; g1 = u1; g2 = u2; g3 = u3;
                g4 = u4; g5 = u5; g6 = u6; g7 = u7;
            }
            float2 f0 = __half22float2(g0), f1 = __half22float2(g1);
            float2 f2 = __half22float2(g2), f3 = __half22float2(g3);
            float2 f4_ = __half22float2(g4), f5 = __half22float2(g5);
            float2 f6 = __half22float2(g6), f7 = __half22float2(g7);
            ax0 += f0.x; ay0 += f0.y; ax1 += f1.x; ay1 += f1.y;
            ax2 += f2.x; ay2 += f2.y; ax3 += f3.x; ay3 += f3.y;
            ax0 += f4_.x; ay0 += f4_.y; ax1 += f5.x; ay1 += f5.y;
            ax2 += f6.x; ay2 += f6.y; ax3 += f7.x; ay3 += f7.y;
        }
        float sx = (ax0 + ax1) + (ax2 + ax3);
        float sy = (ay0 + ay1) + (ay2 + ay3);
        float2 selff = __half22float2(*(const __half2*)(tbase + (size_t)row * 128));
        float rx = fmaxf(dr * (selff.x + sx) + blv.x, 0.f);
        float ry = fmaxf(dr * (selff.y + sy) + blv.y, 0.f);
        if constexpr (__is_same(OutT, __half)) {
            *(__half2*)(out + (size_t)row * HID + 2 * m) = __floats2half2_rn(rx, ry);
        } else {
            *(float2*)(out + (size_t)row * HID + 2 * m) = make_float2(rx, ry);
        }
    }
}

__global__ __launch_bounds__(256) void pool_kernel(const float* __restrict__ h,
                                                   const int* __restrict__ batch,
                                                   const float* __restrict__ Wout,
                                                   const float* __restrict__ bout,
                                                   float* __restrict__ d_out, int n) {
    __shared__ float ssum[4][64];
    __shared__ float smax[4][64];
    int g = blockIdx.x;
    int wave = threadIdx.x >> 6, j = threadIdx.x & 63;
    int lo = 0, hi = n;
    while (lo < hi) { int mid = (lo + hi) >> 1; if (batch[mid] < g) lo = mid + 1; else hi = mid; }
    int start = lo;
    hi = n;
    while (lo < hi) { int mid = (lo + hi) >> 1; if (batch[mid] < g + 1) lo = mid + 1; else hi = mid; }
    int end = lo;

    float sum = 0.f, mx = 0.f;
    for (int i = start + wave; i < end; i += 4) {
        float v = h[(size_t)i * HID + j];
        sum += v;
        mx = fmaxf(mx, v);
    }
    ssum[wave][j] = sum;
    smax[wave][j] = mx;
    __syncthreads();
    if (wave == 0) {
        sum = (ssum[0][j] + ssum[1][j]) + (ssum[2][j] + ssum[3][j]);
        mx = fmaxf(fmaxf(smax[0][j], smax[1][j]), fmaxf(smax[2][j], smax[3][j]));
        float cnt = (float)(end - start);
        float mean = sum / fmaxf(cnt, 1.f);
        float* pooled = d_out + NUM_GRAPHS;
        pooled[(size_t)g * (2 * HID) + j] = mean;
        pooled[(size_t)g * (2 * HID) + HID + j] = mx;
        float c = mean * Wout[j] + mx * Wout[HID + j];
#pragma unroll
        for (int off = 32; off; off >>= 1) c += __shfl_down(c, off);
        if (j == 0) d_out[g] = c + bout[0];
    }
}

// ---------------- launch ----------------

extern "C" void kernel_launch(void* const* d_in, const int* in_sizes, int n_in,
                              void* d_out, int out_size, void* d_ws, size_t ws_size,
                              hipStream_t stream) {
    const float* x    = (const float*)d_in[0];
    const int*   edge = (const int*)d_in[1];
    const int*   batch= (const int*)d_in[2];
    const float* W1 = (const float*)d_in[3];  const float* b1 = (const float*)d_in[4];
    const float* W2 = (const float*)d_in[5];  const float* b2 = (const float*)d_in[6];
    const float* W3 = (const float*)d_in[7];  const float* b3 = (const float*)d_in[8];
    const float* W4 = (const float*)d_in[9];  const float* b4 = (const float*)d_in[10];
    const float* Wout = (const float*)d_in[11]; const float* bout = (const float*)d_in[12];
    float* out = (float*)d_out;

    const int N = N_NODES;
    const int E = in_sizes[1] / 2;
    const int* src = edge;
    const int* dst = edge + E;
    const int chunk = (E + NCHUNK - 1) / NCHUNK;

    char* p = (char*)d_ws;
    auto alloc = [&](size_t bytes) -> char* {
        char* r = p;
        p += (bytes + 255) & ~(size_t)255;
        return r;
    };
    int*      pdeg     = (int*)alloc((size_t)N * 4);
    int*      row_ptr  = (int*)alloc((size_t)(N + 1) * 4);
    int*      partial  = (int*)alloc((size_t)TOTP * 4);
    int*      pincl    = (int*)alloc((size_t)TOTP * 4);
    int*      pbase    = (int*)alloc((size_t)TOTP * 4);
    int*      part_off = (int*)alloc((size_t)(NBUCK + 1) * 4);
    unsigned* part     = (unsigned*)alloc((size_t)1600000 * 4);
    unsigned* cne      = (unsigned*)alloc((size_t)CNE_MAX * 4);
    float*    dis      = (float*)alloc((size_t)N * 4);
    int*      bsum     = (int*)alloc(256 * 4);
    __half*   tmp      = (__half*)alloc((size_t)(N + 1) * HID * 2);
    float*    hA       = (float*)alloc((size_t)N * HID * 4);
    __half*   hH       = (__half*)hA;   // fp16 h aliases front of hA (hA dead until agg4)

    unsigned* padrow = (unsigned*)(tmp + (size_t)N * HID);
    hist_partial<<<NCHUNK, 256, 0, stream>>>(dst, partial, E, chunk, padrow, padrow);
    int nbp = (TOTP + 1023) / 1024;   // 196
    scan1<<<nbp, 256, 0, stream>>>(partial, pincl, bsum, TOTP, 0);
    scan3p<<<(TOTP + 255) / 256, 256, 0, stream>>>(partial, pincl, bsum, nbp, pbase, part_off, E);
    partition_edges<<<NCHUNK, 256, 0, stream>>>(src, dst, pbase, part, E, chunk);
    deg_dis<<<NBUCK, 256, 0, stream>>>(part, part_off, pdeg, dis, N);

    int nb = (N + 1023) / 1024;   // 98
    scan1<<<nb, 256, 0, stream>>>(pdeg, row_ptr + 1, bsum, N, 1);
    scan3<<<(N + 255) / 256, 256, 0, stream>>>(row_ptr, bsum, nb, N);
    build_csr<<<NBUCK, 256, 0, stream>>>(part, part_off, row_ptr, cne, N);

    const int AGG_BLOCKS = 2048;
    const int GEMM_BLOCKS = 1024;

    gemm_mfma<IN_DIM, float><<<GEMM_BLOCKS, 256, 0, stream>>>(x, W1, dis, tmp, N);
    aggregate2<__half><<<AGG_BLOCKS, 256, 0, stream>>>(tmp, dis, row_ptr, cne, b1, hH, N);
    gemm_mfma<HID, _Float16><<<GEMM_BLOCKS, 256, 0, stream>>>((_Float16*)hH, W2, dis, tmp, N);
    aggregate2<__half><<<AGG_BLOCKS, 256, 0, stream>>>(tmp, dis, row_ptr, cne, b2, hH, N);
    gemm_mfma<HID, _Float16><<<GEMM_BLOCKS, 256, 0, stream>>>((_Float16*)hH, W3, dis, tmp, N);
    aggregate2<__half><<<AGG_BLOCKS, 256, 0, stream>>>(tmp, dis, row_ptr, cne, b3, hH, N);
    gemm_mfma<HID, _Float16><<<GEMM_BLOCKS, 256, 0, stream>>>((_Float16*)hH, W4, dis, tmp, N);
    aggregate2<float><<<AGG_BLOCKS, 256, 0, stream>>>(tmp, dis, row_ptr, cne, b4, hA, N);

    pool_kernel<<<NUM_GRAPHS, 256, 0, stream>>>(hA, batch, Wout, bout, out, N);
}

// Round 11
// 337.713 us; speedup vs baseline: 1.4940x; 1.0476x over previous
//
#include <hip/hip_runtime.h>
#include <hip/hip_fp16.h>

#define N_NODES 100000
#define IN_DIM 128
#define HID 64
#define NUM_GRAPHS 2048
#define CNE_MAX (1600000 + 7 * N_NODES)   // padded-to-8 CSR upper bound
#define BROWS 128                          // rows per bucket
#define NBUCK ((N_NODES + BROWS - 1) / BROWS)   // 782
#define NCHUNK 256                         // edge chunks (one block each)
#define TOTP (NBUCK * NCHUNK)              // 200192 partial counters
#define CAP 4096                           // LDS staging entries per bucket

typedef _Float16 h8 __attribute__((ext_vector_type(8)));
typedef float f4 __attribute__((ext_vector_type(4)));

// ---------------- build phase (LDS-bucketed, NO per-edge global atomics — round-6 measured
// the direct-atomic alternative at 3.5x worse: 100+ MB write-allocate at 0.87 TB/s) --------

// also zeroes the pad row (row N) of tmp (replaces a memset dispatch)
__global__ __launch_bounds__(256) void hist_partial(const int* __restrict__ dst,
                                                    int* __restrict__ partial,
                                                    int E, int chunk,
                                                    unsigned* __restrict__ padA,
                                                    unsigned* __restrict__ padB) {
    __shared__ int lh[NBUCK];
    int t = threadIdx.x, c = blockIdx.x;
    if (c == 0) {
        if (t < 32) padA[t] = 0;
        else if (t < 64) padB[t - 32] = 0;
    }
    for (int b = t; b < NBUCK; b += 256) lh[b] = 0;
    __syncthreads();
    int lo = c * chunk, hi = min(lo + chunk, E);
    for (int i = lo + t; i < hi; i += 256) atomicAdd(&lh[dst[i] >> 7], 1);
    __syncthreads();
    for (int b = t; b < NBUCK; b += 256) partial[b * NCHUNK + c] = lh[b];
}

// phase 1: per-block (1024 elems) inclusive scan + block sums; pad8 applied when flagged
__global__ void scan1(const int* __restrict__ counts, int* __restrict__ out1,
                      int* __restrict__ bsum, int n, int pad8) {
    __shared__ int s[256];
    int t = threadIdx.x;
    int base = blockIdx.x * 1024 + t * 4;
    int v[4];
#pragma unroll
    for (int i = 0; i < 4; i++) {
        int c = (base + i < n) ? counts[base + i] : 0;
        v[i] = pad8 ? ((c + 7) & ~7) : c;
    }
    int tsum = v[0] + v[1] + v[2] + v[3];
    s[t] = tsum;
    __syncthreads();
    for (int off = 1; off < 256; off <<= 1) {
        int tv = (t >= off) ? s[t - off] : 0;
        __syncthreads();
        s[t] += tv;
        __syncthreads();
    }
    int excl = s[t] - tsum;
    if (t == 255) bsum[blockIdx.x] = s[255];
    int run = excl;
#pragma unroll
    for (int i = 0; i < 4; i++) {
        run += v[i];
        if (base + i < n) out1[base + i] = run;
    }
}

// scan of block sums (nb <= 256) done redundantly per block in LDS (removes scan2 dispatch)
__device__ __forceinline__ void inline_bscan(const int* __restrict__ bsum, int nb, int* s) {
    int t = threadIdx.x;
    int v = (t < nb) ? bsum[t] : 0;
    s[t] = v;
    __syncthreads();
    for (int off = 1; off < 256; off <<= 1) {
        int tv = (t >= off) ? s[t - off] : 0;
        __syncthreads();
        s[t] += tv;
        __syncthreads();
    }
    int excl = s[t] - v;
    __syncthreads();
    s[t] = excl;
    __syncthreads();
}

__global__ __launch_bounds__(256) void scan3(int* __restrict__ row_ptr,
                                             const int* __restrict__ bsum, int nb, int n) {
    __shared__ int s[256];
    inline_bscan(bsum, nb, s);
    int i = blockIdx.x * blockDim.x + threadIdx.x;
    if (i == 0) row_ptr[0] = 0;
    if (i < n) row_ptr[i + 1] += s[i >> 10];
}

__global__ __launch_bounds__(256) void scan3p(const int* __restrict__ partial,
                                              const int* __restrict__ pincl,
                                              const int* __restrict__ bsum, int nb,
                                              int* __restrict__ base,
                                              int* __restrict__ part_off, int E) {
    __shared__ int s[256];
    inline_bscan(bsum, nb, s);
    int i = blockIdx.x * blockDim.x + threadIdx.x;
    if (i < TOTP) {
        int v = pincl[i] + s[i >> 10] - partial[i];
        base[i] = v;
        if ((i & (NCHUNK - 1)) == 0) part_off[i / NCHUNK] = v;
    }
    if (i == 0) part_off[NBUCK] = E;
}

__global__ __launch_bounds__(256) void partition_edges(const int* __restrict__ src,
                                                       const int* __restrict__ dst,
                                                       const int* __restrict__ base,
                                                       unsigned* __restrict__ part,
                                                       int E, int chunk) {
    __shared__ int cur[NBUCK];
    int t = threadIdx.x, c = blockIdx.x;
    for (int b = t; b < NBUCK; b += 256) cur[b] = base[b * NCHUNK + c];
    __syncthreads();
    int lo = c * chunk, hi = min(lo + chunk, E);
    for (int i = lo + t; i < hi; i += 256) {
        int s = src[i], d = dst[i];
        int pos = atomicAdd(&cur[d >> 7], 1);
        part[pos] = (unsigned)s | ((unsigned)(d & (BROWS - 1)) << 17);
    }
}

__global__ __launch_bounds__(256) void deg_dis(const unsigned* __restrict__ part,
                                               const int* __restrict__ part_off,
                                               int* __restrict__ pdeg,
                                               float* __restrict__ dis, int n) {
    __shared__ int cnt[BROWS];
    int t = threadIdx.x, b = blockIdx.x;
    int r0 = b * BROWS;
    if (t < BROWS) cnt[t] = 0;
    __syncthreads();
    for (int i = part_off[b] + t; i < part_off[b + 1]; i += 256)
        atomicAdd(&cnt[part[i] >> 17], 1);
    __syncthreads();
    int nrows = min(BROWS, n - r0);
    if (t < nrows) {
        int dg = cnt[t];
        pdeg[r0 + t] = dg;                          // raw; scan1 applies pad8
        dis[r0 + t] = rsqrtf((float)(dg + 1));
    }
}

// stage/cne hold BYTE offsets (src * 128); pad slots -> N_NODES*128 (zero row).
__global__ __launch_bounds__(256) void build_csr(const unsigned* __restrict__ part,
                                                 const int* __restrict__ part_off,
                                                 const int* __restrict__ row_ptr,
                                                 unsigned* __restrict__ cne, int n) {
    __shared__ int fill[BROWS];
    __shared__ unsigned stage[CAP];
    int b = blockIdx.x;
    int r0 = b * BROWS;
    int t = threadIdx.x;
    int nrows = min(BROWS, n - r0);
    int base = row_ptr[r0];
    int region = row_ptr[r0 + nrows] - base;
    for (int r = t; r < nrows; r += 256) fill[r] = row_ptr[r0 + r] - base;
    int i0 = part_off[b], i1 = part_off[b + 1];
    if (region <= CAP) {
        for (int i = t; i < region; i += 256) stage[i] = (unsigned)N_NODES << 7;
        __syncthreads();
        for (int i = i0 + t; i < i1; i += 256) {
            unsigned pe = part[i];
            int pos = atomicAdd(&fill[pe >> 17], 1);
            stage[pos] = (pe & 0x1FFFFu) << 7;
        }
        __syncthreads();
        for (int i = t; i < region; i += 256) cne[base + i] = stage[i];
    } else {
        for (int i = t; i < region; i += 256) cne[base + i] = (unsigned)N_NODES << 7;
        __syncthreads();
        for (int i = i0 + t; i < i1; i += 256) {
            unsigned pe = part[i];
            int pos = atomicAdd(&fill[pe >> 17], 1);
            cne[base + pos] = (pe & 0x1FFFFu) << 7;
        }
    }
}

// ---------------- per-layer compute ----------------

// MFMA GEMM: out[row][col] = (half) dis[row] * sum_k X[row][k] * W[k][col]
// XT = float (layer 1) or _Float16 (h from previous layer; A-frag = direct 16 B load).
template <int K, typename XT>
__global__ __launch_bounds__(256) void gemm_mfma(const XT* __restrict__ X,
                                                 const float* __restrict__ W,
                                                 const float* __restrict__ dis,
                                                 __half* __restrict__ out, int n) {
    const int KS = K / 32;
    int wave = threadIdx.x >> 6, lane = threadIdx.x & 63;
    int quad = lane >> 4, l16 = lane & 15;
    h8 b[4][KS];
#pragma unroll
    for (int ct = 0; ct < 4; ct++)
#pragma unroll
        for (int ks = 0; ks < KS; ks++)
#pragma unroll
            for (int j = 0; j < 8; j++)
                b[ct][ks][j] = (_Float16)W[(ks * 32 + quad * 8 + j) * HID + ct * 16 + l16];
    int ntile = n >> 4;
    int wpb = blockDim.x >> 6;
    int stride = gridDim.x * wpb;
    for (int rt = blockIdx.x * wpb + wave; rt < ntile; rt += stride) {
        int row0 = rt << 4;
        const XT* xr = X + (size_t)(row0 + l16) * K + quad * 8;
        f4 acc[4];
#pragma unroll
        for (int ct = 0; ct < 4; ct++) acc[ct] = (f4)(0.f);
#pragma unroll
        for (int ks = 0; ks < KS; ks++) {
            h8 a;
            if constexpr (__is_same(XT, float)) {
                float4 xa = *(const float4*)(xr + ks * 32);
                float4 xb = *(const float4*)(xr + ks * 32 + 4);
                a[0] = (_Float16)xa.x; a[1] = (_Float16)xa.y;
                a[2] = (_Float16)xa.z; a[3] = (_Float16)xa.w;
                a[4] = (_Float16)xb.x; a[5] = (_Float16)xb.y;
                a[6] = (_Float16)xb.z; a[7] = (_Float16)xb.w;
            } else {
                a = *(const h8*)(xr + ks * 32);
            }
#pragma unroll
            for (int ct = 0; ct < 4; ct++)
                acc[ct] = __builtin_amdgcn_mfma_f32_16x16x32_f16(a, b[ct][ks], acc[ct], 0, 0, 0);
        }
        int r0 = row0 + quad * 4;
        float4 dv = *(const float4*)(dis + r0);
        float dd[4] = {dv.x, dv.y, dv.z, dv.w};
#pragma unroll
        for (int reg = 0; reg < 4; reg++) {
            __half* orow = out + (size_t)(r0 + reg) * HID + l16;
            orow[0]  = __float2half(dd[reg] * acc[0][reg]);
            orow[16] = __float2half(dd[reg] * acc[1][reg]);
            orow[32] = __float2half(dd[reg] * acc[2][reg]);
            orow[48] = __float2half(dd[reg] * acc[3][reg]);
        }
    }
}

// out[row] = relu( dis[row] * (tmp[row] + sum_cols tmp[col]) + bias ); pads read zero row N.
// Dual-row lane layout: 64 lanes = 32 column-pairs (m) x 2 rows (hh): only 2 distinct
// random rows per VMEM instruction (the measured sweet spot: 2-4 rows/instr = 40 us/layer;
// 8-16 rows/instr (sliced variants) = 48-51 us despite halved FETCH). Lane owns row 2p+hh,
// processes all 8 edges per group: 2 uint4 idx loads + 8 gathers in flight (16 w/ depth-2
// prefetch). Plain cached idx loads: R10 measured nontemporal hints at +10 us (wave-
// broadcast idx lines are NOT single-touch; uncached loads repeat full-latency trips).
template <typename OutT>
__global__ __launch_bounds__(256) void aggregate2(const __half* __restrict__ tmp,
                                                  const float* __restrict__ dis,
                                                  const int* __restrict__ row_ptr,
                                                  const unsigned* __restrict__ cne,
                                                  const float* __restrict__ bias,
                                                  OutT* __restrict__ out, int n) {
    int wave = threadIdx.x >> 6, lane = threadIdx.x & 63;
    int m = lane & 31, hh = lane >> 5;
    const char* tbase = (const char*)tmp + 4 * m;   // lane's column-pair byte base
    int wpb = blockDim.x >> 6;
    int stride = gridDim.x * wpb;
    float2 blv = *(const float2*)(bias + 2 * m);
    int npairs = n >> 1;
    for (int p = blockIdx.x * wpb + wave; p < npairs; p += stride) {
        int row = 2 * p + hh;
        float dr = dis[row];
        int s = row_ptr[row], e = row_ptr[row + 1];
        int ng = (e - s) >> 3;   // 8-edge groups (rows padded to 8)
        float ax0 = 0.f, ay0 = 0.f, ax1 = 0.f, ay1 = 0.f;
        float ax2 = 0.f, ay2 = 0.f, ax3 = 0.f, ay3 = 0.f;
        if (ng > 0) {
            const uint4* ip = (const uint4*)(cne + s);
            uint4 A0 = ip[0], A1 = ip[1];
            __half2 g0 = *(const __half2*)(tbase + A0.x);
            __half2 g1 = *(const __half2*)(tbase + A0.y);
            __half2 g2 = *(const __half2*)(tbase + A0.z);
            __half2 g3 = *(const __half2*)(tbase + A0.w);
            __half2 g4 = *(const __half2*)(tbase + A1.x);
            __half2 g5 = *(const __half2*)(tbase + A1.y);
            __half2 g6 = *(const __half2*)(tbase + A1.z);
            __half2 g7 = *(const __half2*)(tbase + A1.w);
            uint4 B0, B1;
            if (ng > 1) { B0 = ip[2]; B1 = ip[3]; }
            for (int g = 1; g < ng; g++) {
                __half2 u0 = *(const __half2*)(tbase + B0.x);
                __half2 u1 = *(const __half2*)(tbase + B0.y);
                __half2 u2 = *(const __half2*)(tbase + B0.z);
                __half2 u3 = *(const __half2*)(tbase + B0.w);
                __half2 u4 = *(const __half2*)(tbase + B1.x);
                __half2 u5 = *(const __half2*)(tbase + B1.y);
                __half2 u6 = *(const __half2*)(tbase + B1.z);
                __half2 u7 = *(const __half2*)(tbase + B1.w);
                if (g + 1 < ng) { B0 = ip[2 * (g + 1)]; B1 = ip[2 * (g + 1) + 1]; }
                float2 f0 = __half22float2(g0), f1 = __half22float2(g1);
                float2 f2 = __half22float2(g2), f3 = __half22float2(g3);
                float2 f4_ = __half22float2(g4), f5 = __half22float2(g5);
                float2 f6 = __half22float2(g6), f7 = __half22float2(g7);
                ax0 += f0.x; ay0 += f0.y; ax1 += f1.x; ay1 += f1.y;
                ax2 += f2.x; ay2 += f2.y; ax3 += f3.x; ay3 += f3.y;
                ax0 += f4_.x; ay0 += f4_.y; ax1 += f5.x; ay1 += f5.y;
                ax2 += f6.x; ay2 += f6.y; ax3 += f7.x; ay3 += f7.y;
                g0 = u0; g1 = u1; g2 = u2; g3 = u3;
                g4 = u4; g5 = u5; g6 = u6; g7 = u7;
            }
            float2 f0 = __half22float2(g0), f1 = __half22float2(g1);
            float2 f2 = __half22float2(g2), f3 = __half22float2(g3);
            float2 f4_ = __half22float2(g4), f5 = __half22float2(g5);
            float2 f6 = __half22float2(g6), f7 = __half22float2(g7);
            ax0 += f0.x; ay0 += f0.y; ax1 += f1.x; ay1 += f1.y;
            ax2 += f2.x; ay2 += f2.y; ax3 += f3.x; ay3 += f3.y;
            ax0 += f4_.x; ay0 += f4_.y; ax1 += f5.x; ay1 += f5.y;
            ax2 += f6.x; ay2 += f6.y; ax3 += f7.x; ay3 += f7.y;
        }
        float sx = (ax0 + ax1) + (ax2 + ax3);
        float sy = (ay0 + ay1) + (ay2 + ay3);
        float2 selff = __half22float2(*(const __half2*)(tbase + (size_t)row * 128));
        float rx = fmaxf(dr * (selff.x + sx) + blv.x, 0.f);
        float ry = fmaxf(dr * (selff.y + sy) + blv.y, 0.f);
        if constexpr (__is_same(OutT, __half)) {
            *(__half2*)(out + (size_t)row * HID + 2 * m) = __floats2half2_rn(rx, ry);
        } else {
            *(float2*)(out + (size_t)row * HID + 2 * m) = make_float2(rx, ry);
        }
    }
}

__global__ __launch_bounds__(256) void pool_kernel(const float* __restrict__ h,
                                                   const int* __restrict__ batch,
                                                   const float* __restrict__ Wout,
                                                   const float* __restrict__ bout,
                                                   float* __restrict__ d_out, int n) {
    __shared__ float ssum[4][64];
    __shared__ float smax[4][64];
    int g = blockIdx.x;
    int wave = threadIdx.x >> 6, j = threadIdx.x & 63;
    int lo = 0, hi = n;
    while (lo < hi) { int mid = (lo + hi) >> 1; if (batch[mid] < g) lo = mid + 1; else hi = mid; }
    int start = lo;
    hi = n;
    while (lo < hi) { int mid = (lo + hi) >> 1; if (batch[mid] < g + 1) lo = mid + 1; else hi = mid; }
    int end = lo;

    float sum = 0.f, mx = 0.f;
    for (int i = start + wave; i < end; i += 4) {
        float v = h[(size_t)i * HID + j];
        sum += v;
        mx = fmaxf(mx, v);
    }
    ssum[wave][j] = sum;
    smax[wave][j] = mx;
    __syncthreads();
    if (wave == 0) {
        sum = (ssum[0][j] + ssum[1][j]) + (ssum[2][j] + ssum[3][j]);
        mx = fmaxf(fmaxf(smax[0][j], smax[1][j]), fmaxf(smax[2][j], smax[3][j]));
        float cnt = (float)(end - start);
        float mean = sum / fmaxf(cnt, 1.f);
        float* pooled = d_out + NUM_GRAPHS;
        pooled[(size_t)g * (2 * HID) + j] = mean;
        pooled[(size_t)g * (2 * HID) + HID + j] = mx;
        float c = mean * Wout[j] + mx * Wout[HID + j];
#pragma unroll
        for (int off = 32; off; off >>= 1) c += __shfl_down(c, off);
        if (j == 0) d_out[g] = c + bout[0];
    }
}

// ---------------- launch ----------------

extern "C" void kernel_launch(void* const* d_in, const int* in_sizes, int n_in,
                              void* d_out, int out_size, void* d_ws, size_t ws_size,
                              hipStream_t stream) {
    const float* x    = (const float*)d_in[0];
    const int*   edge = (const int*)d_in[1];
    const int*   batch= (const int*)d_in[2];
    const float* W1 = (const float*)d_in[3];  const float* b1 = (const float*)d_in[4];
    const float* W2 = (const float*)d_in[5];  const float* b2 = (const float*)d_in[6];
    const float* W3 = (const float*)d_in[7];  const float* b3 = (const float*)d_in[8];
    const float* W4 = (const float*)d_in[9];  const float* b4 = (const float*)d_in[10];
    const float* Wout = (const float*)d_in[11]; const float* bout = (const float*)d_in[12];
    float* out = (float*)d_out;

    const int N = N_NODES;
    const int E = in_sizes[1] / 2;
    const int* src = edge;
    const int* dst = edge + E;
    const int chunk = (E + NCHUNK - 1) / NCHUNK;

    char* p = (char*)d_ws;
    auto alloc = [&](size_t bytes) -> char* {
        char* r = p;
        p += (bytes + 255) & ~(size_t)255;
        return r;
    };
    int*      pdeg     = (int*)alloc((size_t)N * 4);
    int*      row_ptr  = (int*)alloc((size_t)(N + 1) * 4);
    int*      partial  = (int*)alloc((size_t)TOTP * 4);
    int*      pincl    = (int*)alloc((size_t)TOTP * 4);
    int*      pbase    = (int*)alloc((size_t)TOTP * 4);
    int*      part_off = (int*)alloc((size_t)(NBUCK + 1) * 4);
    unsigned* part     = (unsigned*)alloc((size_t)1600000 * 4);
    unsigned* cne      = (unsigned*)alloc((size_t)CNE_MAX * 4);
    float*    dis      = (float*)alloc((size_t)N * 4);
    int*      bsum     = (int*)alloc(256 * 4);
    __half*   tmp      = (__half*)alloc((size_t)(N + 1) * HID * 2);
    float*    hA       = (float*)alloc((size_t)N * HID * 4);
    __half*   hH       = (__half*)hA;   // fp16 h aliases front of hA (hA dead until agg4)

    unsigned* padrow = (unsigned*)(tmp + (size_t)N * HID);
    hist_partial<<<NCHUNK, 256, 0, stream>>>(dst, partial, E, chunk, padrow, padrow);
    int nbp = (TOTP + 1023) / 1024;   // 196
    scan1<<<nbp, 256, 0, stream>>>(partial, pincl, bsum, TOTP, 0);
    scan3p<<<(TOTP + 255) / 256, 256, 0, stream>>>(partial, pincl, bsum, nbp, pbase, part_off, E);
    partition_edges<<<NCHUNK, 256, 0, stream>>>(src, dst, pbase, part, E, chunk);
    deg_dis<<<NBUCK, 256, 0, stream>>>(part, part_off, pdeg, dis, N);

    int nb = (N + 1023) / 1024;   // 98
    scan1<<<nb, 256, 0, stream>>>(pdeg, row_ptr + 1, bsum, N, 1);
    scan3<<<(N + 255) / 256, 256, 0, stream>>>(row_ptr, bsum, nb, N);
    build_csr<<<NBUCK, 256, 0, stream>>>(part, part_off, row_ptr, cne, N);

    const int AGG_BLOCKS = 2048;
    const int GEMM_BLOCKS = 1024;

    gemm_mfma<IN_DIM, float><<<GEMM_BLOCKS, 256, 0, stream>>>(x, W1, dis, tmp, N);
    aggregate2<__half><<<AGG_BLOCKS, 256, 0, stream>>>(tmp, dis, row_ptr, cne, b1, hH, N);
    gemm_mfma<HID, _Float16><<<GEMM_BLOCKS, 256, 0, stream>>>((_Float16*)hH, W2, dis, tmp, N);
    aggregate2<__half><<<AGG_BLOCKS, 256, 0, stream>>>(tmp, dis, row_ptr, cne, b2, hH, N);
    gemm_mfma<HID, _Float16><<<GEMM_BLOCKS, 256, 0, stream>>>((_Float16*)hH, W3, dis, tmp, N);
    aggregate2<__half><<<AGG_BLOCKS, 256, 0, stream>>>(tmp, dis, row_ptr, cne, b3, hH, N);
    gemm_mfma<HID, _Float16><<<GEMM_BLOCKS, 256, 0, stream>>>((_Float16*)hH, W4, dis, tmp, N);
    aggregate2<float><<<AGG_BLOCKS, 256, 0, stream>>>(tmp, dis, row_ptr, cne, b4, hA, N);

    pool_kernel<<<NUM_GRAPHS, 256, 0, stream>>>(hA, batch, Wout, bout, out, N);
}